// Round 6
// baseline (206.478 us; speedup 1.0000x reference)
//
#include <hip/hip_runtime.h>
#include <hip/hip_bf16.h>

typedef __bf16 bf16x8_t __attribute__((ext_vector_type(8)));
typedef __bf16 bf16x4_t __attribute__((ext_vector_type(4)));
typedef float f32x4_t __attribute__((ext_vector_type(4)));

__device__ __forceinline__ void gload_lds16(const void* g, void* l) {
    __builtin_amdgcn_global_load_lds((const __attribute__((address_space(1))) void*)g,
                                     (__attribute__((address_space(3))) void*)l, 16, 0, 0);
}

// ---------------- fp32 -> bf16 conversion ----------------
__global__ void f2bf_kernel(const float* __restrict__ in, __bf16* __restrict__ out, int n) {
    int i = (blockIdx.x * blockDim.x + threadIdx.x) * 4;
    if (i >= n) return;
    float4 v = *(const float4*)(in + i);
    bf16x4_t o;
    o[0] = (__bf16)v.x; o[1] = (__bf16)v.y; o[2] = (__bf16)v.z; o[3] = (__bf16)v.w;
    *(bf16x4_t*)(out + i) = o;
}

// ---------------- deep-pipelined GEMM: C[M,N] = A[M,K] * Bt[N,K]^T ----------------
// BM=128, BN=256, BK=64. 8 waves (2M x 4N), per-wave 64x64.
// 3-deep LDS buffers (144 KB). Ledger: prologue stages tiles 0,1; iter t waits
// vmcnt(6) (drains tile t, leaves tile t+1 in flight), then phases issue tile
// t+2's loads interleaved with ds_reads + MFMA clusters. Buffer (t+2)%3 was
// last read in iter t-1 (its final barrier precedes these issues).
// Staging swizzle: LDS chunk c of row r holds global chunk c^(r&7) (both-sides).
template <typename OutT>
__global__ __launch_bounds__(512, 2) void gemm_dp(const __bf16* __restrict__ A,
                                                  const __bf16* __restrict__ Bt,
                                                  OutT* __restrict__ C,
                                                  int M, int N, int K) {
    __shared__ __bf16 As[3][128 * 64];   // 16 KB per buf
    __shared__ __bf16 Bs[3][256 * 64];   // 32 KB per buf

    const int tid  = threadIdx.x;
    const int lane = tid & 63;
    const int wid  = tid >> 6;
    const int wm   = wid >> 2;      // 0..1
    const int wn   = wid & 3;       // 0..3

    // XCD swizzle (grid % 8 == 0 -> bijective)
    const int nwg   = gridDim.x;
    const int ntile = N >> 8;
    int fl = blockIdx.x;
    fl = (fl & 7) * (nwg >> 3) + (fl >> 3);
    const int m0 = (fl / ntile) * 128;
    const int n0 = (fl % ntile) * 256;

    const int lr = lane & 15;
    const int lg = lane >> 4;
    const int cr = lg * 4;
    // staging: lane covers row srow of an 8-row segment; source chunk pre-swizzled
    const int srow = lane >> 3;
    const int gcol = (((lane & 7) ^ srow) << 3);

    f32x4_t acc[4][4];
#pragma unroll
    for (int i = 0; i < 4; ++i)
#pragma unroll
        for (int j = 0; j < 4; ++j)
            acc[i][j] = (f32x4_t){0.f, 0.f, 0.f, 0.f};

    const int NT = K >> 6;

    // A: 16 segments of 8 rows (2 per wave); B: 32 segments (4 per wave).
    auto stageA_B0 = [&](int kt, int buf) {   // 4 loads: A segs {w,w+8}, B segs {w,w+8}
        const __bf16* Ab = A + (size_t)m0 * K + kt * 64;
        const __bf16* Bb = Bt + (size_t)n0 * K + kt * 64;
        __bf16* Al = &As[buf][0];
        __bf16* Bl = &Bs[buf][0];
        gload_lds16(Ab + (size_t)(wid * 8 + srow) * K + gcol,        Al + wid * 512);
        gload_lds16(Ab + (size_t)((wid + 8) * 8 + srow) * K + gcol,  Al + (wid + 8) * 512);
        gload_lds16(Bb + (size_t)(wid * 8 + srow) * K + gcol,        Bl + wid * 512);
        gload_lds16(Bb + (size_t)((wid + 8) * 8 + srow) * K + gcol,  Bl + (wid + 8) * 512);
    };
    auto stageB1 = [&](int kt, int buf) {     // 2 loads: B segs {w+16,w+24}
        const __bf16* Bb = Bt + (size_t)n0 * K + kt * 64;
        __bf16* Bl = &Bs[buf][0];
        gload_lds16(Bb + (size_t)((wid + 16) * 8 + srow) * K + gcol, Bl + (wid + 16) * 512);
        gload_lds16(Bb + (size_t)((wid + 24) * 8 + srow) * K + gcol, Bl + (wid + 24) * 512);
    };

    // prologue: tiles 0 and 1
    stageA_B0(0, 0); stageB1(0, 0);
    stageA_B0(1, 1); stageB1(1, 1);

    for (int kt = 0; kt < NT; ++kt) {
        const int cur = kt % 3;
        const int b2  = (kt + 2) % 3;
        const bool pf = (kt + 2 < NT);

        if (kt + 1 < NT) asm volatile("s_waitcnt vmcnt(6)" ::: "memory");
        else             asm volatile("s_waitcnt vmcnt(0)" ::: "memory");
        __builtin_amdgcn_sched_barrier(0);
        __builtin_amdgcn_s_barrier();
        __builtin_amdgcn_sched_barrier(0);

        const __bf16* Al = &As[cur][0];
        const __bf16* Bl = &Bs[cur][0];

        // ---- phase 0: issue 4 loads of tile kt+2, read A + B(p0), MFMA nf=0,1 ----
        if (pf) stageA_B0(kt + 2, b2);

        bf16x8_t af[4][2];
#pragma unroll
        for (int mf = 0; mf < 4; ++mf)
#pragma unroll
            for (int kk = 0; kk < 2; ++kk) {
                const int row = wm * 64 + mf * 16 + lr;
                const int g   = kk * 4 + lg;
                af[mf][kk] = *(const bf16x8_t*)&Al[row * 64 + ((g ^ (row & 7)) << 3)];
            }
        bf16x8_t bfr[2][2];
#pragma unroll
        for (int nf = 0; nf < 2; ++nf)
#pragma unroll
            for (int kk = 0; kk < 2; ++kk) {
                const int row = wn * 64 + nf * 16 + lr;
                const int g   = kk * 4 + lg;
                bfr[nf][kk] = *(const bf16x8_t*)&Bl[row * 64 + ((g ^ (row & 7)) << 3)];
            }
        __builtin_amdgcn_s_setprio(1);
#pragma unroll
        for (int mf = 0; mf < 4; ++mf)
#pragma unroll
            for (int nf = 0; nf < 2; ++nf) {
                acc[mf][nf] = __builtin_amdgcn_mfma_f32_16x16x32_bf16(af[mf][0], bfr[nf][0], acc[mf][nf], 0, 0, 0);
                acc[mf][nf] = __builtin_amdgcn_mfma_f32_16x16x32_bf16(af[mf][1], bfr[nf][1], acc[mf][nf], 0, 0, 0);
            }
        __builtin_amdgcn_s_setprio(0);
        __builtin_amdgcn_s_barrier();

        // ---- phase 1: issue last 2 loads of tile kt+2, read B(p1), MFMA nf=2,3 ----
        if (pf) stageB1(kt + 2, b2);
#pragma unroll
        for (int nf = 0; nf < 2; ++nf)
#pragma unroll
            for (int kk = 0; kk < 2; ++kk) {
                const int row = wn * 64 + (2 + nf) * 16 + lr;
                const int g   = kk * 4 + lg;
                bfr[nf][kk] = *(const bf16x8_t*)&Bl[row * 64 + ((g ^ (row & 7)) << 3)];
            }
        __builtin_amdgcn_s_setprio(1);
#pragma unroll
        for (int mf = 0; mf < 4; ++mf)
#pragma unroll
            for (int nf = 0; nf < 2; ++nf) {
                acc[mf][2 + nf] = __builtin_amdgcn_mfma_f32_16x16x32_bf16(af[mf][0], bfr[nf][0], acc[mf][2 + nf], 0, 0, 0);
                acc[mf][2 + nf] = __builtin_amdgcn_mfma_f32_16x16x32_bf16(af[mf][1], bfr[nf][1], acc[mf][2 + nf], 0, 0, 0);
            }
        __builtin_amdgcn_s_setprio(0);
        __builtin_amdgcn_s_barrier();
    }

#pragma unroll
    for (int mf = 0; mf < 4; ++mf)
#pragma unroll
        for (int nf = 0; nf < 4; ++nf)
#pragma unroll
            for (int r = 0; r < 4; ++r) {
                int row = m0 + wm * 64 + mf * 16 + cr + r;
                int col = n0 + wn * 64 + nf * 16 + lr;
                C[(size_t)row * N + col] = (OutT)acc[mf][nf][r];
            }
}

// ---------------- flash attention (causal), v4 (unchanged) ----------------
__global__ __launch_bounds__(512, 4) void attn_kernel(const __bf16* __restrict__ qkv,
                                                      __bf16* __restrict__ y) {
    const int T = 2048, C3 = 3072;
    const int orig = blockIdx.x;
    const int bidx = ((orig & 7) << 6) + (orig >> 3);
    const int pair = bidx & 7;
    const int h    = (bidx >> 3) & 15;
    const int b    = bidx >> 7;

    __shared__ __bf16 Ks[128 * 64];
    __shared__ __bf16 Vt[2][64 * 72];
    __shared__ __bf16 Ps[8 * 16 * 136];

    const int tid  = threadIdx.x;
    const int lane = tid & 63;
    const int w    = tid >> 6;
    const int lr   = lane & 15;
    const int lg   = lane >> 4;
    const int lk   = lg * 8;

    const __bf16* qg = qkv + (size_t)b * T * C3 + h * 64;
    const __bf16* kg = qg + 1024;
    const __bf16* vg = qg + 2048;

    const float CE    = 0.125f * 1.44269504f;
    const float DEFER = 44.0f;

    const int r0    = tid >> 3;
    const int kcol  = (tid & 7) * 8;
    const int kslot = ((tid & 7) ^ (r0 & 7)) << 3;
    const int vks   = r0 ^ ((tid & 7) << 3);

    __bf16* Pw = &Ps[w * 16 * 136];

    for (int pass = 0; pass < 2; ++pass) {
        const int qs  = pass ? 15 - pair : pair;
        const int qt0 = qs * 128;
        const int nt  = qs + 1;

        bf16x8_t qf0, qf1;
        {
            const __bf16* qrow = qg + (size_t)(qt0 + w * 16 + lr) * C3;
            qf0 = *(const bf16x8_t*)&qrow[lk];
            qf1 = *(const bf16x8_t*)&qrow[32 + lk];
        }

        bf16x8_t ka = *(const bf16x8_t*)&kg[(size_t)r0 * C3 + kcol];
        bf16x8_t kb = *(const bf16x8_t*)&kg[(size_t)(64 + r0) * C3 + kcol];
        bf16x8_t va = *(const bf16x8_t*)&vg[(size_t)r0 * C3 + kcol];
        bf16x8_t vb = *(const bf16x8_t*)&vg[(size_t)(64 + r0) * C3 + kcol];

        f32x4_t o_acc[4];
#pragma unroll
        for (int i = 0; i < 4; ++i) o_acc[i] = (f32x4_t){0.f, 0.f, 0.f, 0.f};
        float m_r = -3.0e38f, l_r = 0.f;

        for (int t = 0; t < nt; ++t) {
            __syncthreads();

            *(bf16x8_t*)&Ks[r0 * 64 + kslot] = ka;
            *(bf16x8_t*)&Ks[(64 + r0) * 64 + kslot] = kb;
#pragma unroll
            for (int j = 0; j < 8; ++j) Vt[0][(kcol + j) * 72 + vks] = va[j];
#pragma unroll
            for (int j = 0; j < 8; ++j) Vt[1][(kcol + j) * 72 + vks] = vb[j];

            __syncthreads();

            if (t + 1 < nt) {
                const size_t kb0 = (size_t)(t + 1) * 128;
                ka = *(const bf16x8_t*)&kg[(kb0 + r0) * C3 + kcol];
                kb = *(const bf16x8_t*)&kg[(kb0 + 64 + r0) * C3 + kcol];
                va = *(const bf16x8_t*)&vg[(kb0 + r0) * C3 + kcol];
                vb = *(const bf16x8_t*)&vg[(kb0 + 64 + r0) * C3 + kcol];
            }

            f32x4_t s[8];
#pragma unroll
            for (int c = 0; c < 8; ++c) {
                const int key = c * 16 + lr;
                const int sw  = (key & 7) << 3;
                bf16x8_t kfa = *(const bf16x8_t*)&Ks[key * 64 + (lk ^ sw)];
                bf16x8_t kfb = *(const bf16x8_t*)&Ks[key * 64 + ((32 + lk) ^ sw)];
                s[c] = __builtin_amdgcn_mfma_f32_16x16x32_bf16(kfa, qf0, (f32x4_t){0.f, 0.f, 0.f, 0.f}, 0, 0, 0);
                s[c] = __builtin_amdgcn_mfma_f32_16x16x32_bf16(kfb, qf1, s[c], 0, 0, 0);
            }

            if (t == nt - 1) {
                const int ql = w * 16 + lr;
#pragma unroll
                for (int c = 0; c < 8; ++c)
#pragma unroll
                    for (int r = 0; r < 4; ++r)
                        if (c * 16 + lg * 4 + r > ql) s[c][r] = -1.0e30f;
            }

            float pm = s[0][0];
#pragma unroll
            for (int c = 0; c < 8; ++c)
#pragma unroll
                for (int r = 0; r < 4; ++r) pm = fmaxf(pm, s[c][r]);

            if (!__all(pm <= m_r + DEFER)) {
                pm = fmaxf(pm, __shfl_xor(pm, 16));
                pm = fmaxf(pm, __shfl_xor(pm, 32));
                const float mn    = fmaxf(m_r, pm);
                const float alpha = exp2f((m_r - mn) * CE);
                l_r *= alpha;
#pragma unroll
                for (int dt = 0; dt < 4; ++dt)
#pragma unroll
                    for (int r = 0; r < 4; ++r) o_acc[dt][r] *= alpha;
                m_r = mn;
            }
            const float mce = m_r * CE;

            float rs = 0.f;
#pragma unroll
            for (int c = 0; c < 8; ++c) {
                bf16x4_t pk;
#pragma unroll
                for (int r = 0; r < 4; ++r) {
                    float pv = exp2f(fmaf(s[c][r], CE, -mce));
                    rs += pv;
                    pk[r] = (__bf16)pv;
                }
                *(bf16x4_t*)&Pw[lr * 136 + c * 16 + lg * 4] = pk;
            }
            rs += __shfl_xor(rs, 16);
            rs += __shfl_xor(rs, 32);
            l_r += rs;

#pragma unroll
            for (int hf = 0; hf < 2; ++hf) {
                bf16x8_t pb0 = *(const bf16x8_t*)&Pw[lr * 136 + hf * 64 + lk];
                bf16x8_t pb1 = *(const bf16x8_t*)&Pw[lr * 136 + hf * 64 + 32 + lk];
#pragma unroll
                for (int dt = 0; dt < 4; ++dt) {
                    const int d   = dt * 16 + lr;
                    const int sw2 = ((d >> 3) & 7) << 3;
                    bf16x8_t vb0 = *(const bf16x8_t*)&Vt[hf][d * 72 + (lk ^ sw2)];
                    bf16x8_t vb1 = *(const bf16x8_t*)&Vt[hf][d * 72 + ((32 + lk) ^ sw2)];
                    o_acc[dt] = __builtin_amdgcn_mfma_f32_16x16x32_bf16(vb0, pb0, o_acc[dt], 0, 0, 0);
                    o_acc[dt] = __builtin_amdgcn_mfma_f32_16x16x32_bf16(vb1, pb1, o_acc[dt], 0, 0, 0);
                }
            }
        }

        const float inv = 1.0f / l_r;
        const int q = qt0 + w * 16 + lr;
#pragma unroll
        for (int dt = 0; dt < 4; ++dt) {
            bf16x4_t ov;
#pragma unroll
            for (int r = 0; r < 4; ++r) ov[r] = (__bf16)(o_acc[dt][r] * inv);
            *(bf16x4_t*)&y[(size_t)(b * T + q) * 1024 + h * 64 + dt * 16 + lg * 4] = ov;
        }
    }
}

// ---------------- launch ----------------
extern "C" void kernel_launch(void* const* d_in, const int* in_sizes, int n_in,
                              void* d_out, int out_size, void* d_ws, size_t ws_size,
                              hipStream_t stream) {
    const float* x      = (const float*)d_in[0];
    const float* w_attn = (const float*)d_in[1];
    const float* w_proj = (const float*)d_in[2];
    float* out = (float*)d_out;

    char* ws = (char*)d_ws;
    __bf16* xb   = (__bf16*)(ws);                      // 8192*1024   = 16 MB
    __bf16* wab  = (__bf16*)(ws + 16777216);           // 3072*1024   = 6 MB
    __bf16* wpb  = (__bf16*)(ws + 23068672);           // 1024*1024   = 2 MB
    __bf16* qkvb = (__bf16*)(ws + 25165824);           // 8192*3072   = 48 MB
    __bf16* yb   = (__bf16*)(ws + 75497472);           // 8192*1024   = 16 MB

    f2bf_kernel<<<8192, 256, 0, stream>>>(x, xb, 8388608);
    f2bf_kernel<<<3072, 256, 0, stream>>>(w_attn, wab, 3145728);
    f2bf_kernel<<<1024, 256, 0, stream>>>(w_proj, wpb, 1048576);

    // qkv = x @ w_attn^T   [8192, 3072]  (deep-pipelined, 768 blocks = 3 CU-waves)
    gemm_dp<__bf16><<<768, 512, 0, stream>>>(xb, wab, qkvb, 8192, 3072, 1024);

    // flash attention -> yb [8192, 1024]
    attn_kernel<<<512, 512, 0, stream>>>(qkvb, yb);

    // out = yb @ w_proj^T  [8192, 1024] fp32  (256 blocks = 1 CU-wave)
    gemm_dp<float><<<256, 512, 0, stream>>>(yb, wpb, out, 8192, 1024, 1024);
}

// Round 7
// 199.144 us; speedup vs baseline: 1.0368x; 1.0368x over previous
//
#include <hip/hip_runtime.h>
#include <hip/hip_bf16.h>

typedef __bf16 bf16x8_t __attribute__((ext_vector_type(8)));
typedef __bf16 bf16x4_t __attribute__((ext_vector_type(4)));
typedef float f32x4_t __attribute__((ext_vector_type(4)));

__device__ __forceinline__ void gload_lds16(const void* g, void* l) {
    __builtin_amdgcn_global_load_lds((const __attribute__((address_space(1))) void*)g,
                                     (__attribute__((address_space(3))) void*)l, 16, 0, 0);
}

// ---------------- fp32 -> bf16 conversion ----------------
__global__ void f2bf_kernel(const float* __restrict__ in, __bf16* __restrict__ out, int n) {
    int i = (blockIdx.x * blockDim.x + threadIdx.x) * 4;
    if (i >= n) return;
    float4 v = *(const float4*)(in + i);
    bf16x4_t o;
    o[0] = (__bf16)v.x; o[1] = (__bf16)v.y; o[2] = (__bf16)v.z; o[3] = (__bf16)v.w;
    *(bf16x4_t*)(out + i) = o;
}

// ---------------- bf16 GEMM (m97-style 128x128, proven): C = A * Bt^T ----------------
template <typename OutT>
__global__ __launch_bounds__(256) void gemm_bt(const __bf16* __restrict__ A,
                                               const __bf16* __restrict__ Bt,
                                               OutT* __restrict__ C,
                                               int M, int N, int K) {
    __shared__ __bf16 As[128 * 32];
    __shared__ __bf16 Bs[128 * 32];

    const int tid  = threadIdx.x;
    const int lane = tid & 63;
    const int wid  = tid >> 6;
    const int wm   = wid >> 1;
    const int wn   = wid & 1;

    const int nwg = gridDim.x * gridDim.y;
    int fl = blockIdx.y * gridDim.x + blockIdx.x;
    fl = (fl & 7) * (nwg >> 3) + (fl >> 3);
    const int m0 = (fl / gridDim.x) * 128;
    const int n0 = (fl % gridDim.x) * 128;

    const int lr = lane & 15;
    const int lk = (lane >> 4) * 8;
    const int cr = (lane >> 4) * 4;

    f32x4_t acc[4][4];
    for (int i = 0; i < 4; ++i)
        for (int j = 0; j < 4; ++j)
            acc[i][j] = (f32x4_t){0.f, 0.f, 0.f, 0.f};

    for (int k0 = 0; k0 < K; k0 += 32) {
        __syncthreads();
        for (int i = 0; i < 2; ++i) {
            int flat = i * 256 + tid;
            int row  = flat >> 2;
            int col  = (flat & 3) * 8;
            gload_lds16(&A[(size_t)(m0 + row) * K + k0 + col], &As[(size_t)(i * 256 + wid * 64) * 8]);
            gload_lds16(&Bt[(size_t)(n0 + row) * K + k0 + col], &Bs[(size_t)(i * 256 + wid * 64) * 8]);
        }
        __syncthreads();

        bf16x8_t af[4], bfr[4];
        for (int mf = 0; mf < 4; ++mf)
            af[mf] = *(const bf16x8_t*)&As[(wm * 64 + mf * 16 + lr) * 32 + lk];
        for (int nf = 0; nf < 4; ++nf)
            bfr[nf] = *(const bf16x8_t*)&Bs[(wn * 64 + nf * 16 + lr) * 32 + lk];
        for (int mf = 0; mf < 4; ++mf)
            for (int nf = 0; nf < 4; ++nf)
                acc[mf][nf] = __builtin_amdgcn_mfma_f32_16x16x32_bf16(af[mf], bfr[nf], acc[mf][nf], 0, 0, 0);
    }

    for (int mf = 0; mf < 4; ++mf)
        for (int nf = 0; nf < 4; ++nf)
            for (int r = 0; r < 4; ++r) {
                int row = m0 + wm * 64 + mf * 16 + cr + r;
                int col = n0 + wn * 64 + nf * 16 + lr;
                C[(size_t)row * N + col] = (OutT)acc[mf][nf][r];
            }
}

// ---------------- flash attention (causal), v5: 4 waves x 32 q-rows ----------------
// QBLK=128, KVBLK=128, 256 threads. Each wave owns 32 q-rows (2 q-fragments),
// so every K/V fragment ds_read feeds 2 MFMA (operand reuse; LDS-pipe was the
// bottleneck at 8x16). 512 blocks = b(4) x h(16) x pair(8), 2 blocks/CU.
__global__ __launch_bounds__(256, 2) void attn_kernel(const __bf16* __restrict__ qkv,
                                                      __bf16* __restrict__ y) {
    const int T = 2048, C3 = 3072;
    const int orig = blockIdx.x;
    const int bidx = ((orig & 7) << 6) + (orig >> 3);   // XCD swizzle (512 % 8 == 0)
    const int pair = bidx & 7;
    const int h    = (bidx >> 3) & 15;
    const int b    = bidx >> 7;

    __shared__ __bf16 Ks[128 * 64];      // [key][chunk-swizzled dims]
    __shared__ __bf16 Vt[2][64 * 72];    // half: [d][key-slot swizzled]
    __shared__ __bf16 Ps[4 * 32 * 136];  // per-wave [q(32)][key(128)+pad]

    const int tid  = threadIdx.x;
    const int lane = tid & 63;
    const int w    = tid >> 6;          // 0..3
    const int lr   = lane & 15;
    const int lg   = lane >> 4;
    const int lk   = lg * 8;

    const __bf16* qg = qkv + (size_t)b * T * C3 + h * 64;
    const __bf16* kg = qg + 1024;
    const __bf16* vg = qg + 2048;

    const float CE    = 0.125f * 1.44269504f;
    const float DEFER = 44.0f;

    // K staging: thread covers key kr, chunks kc0..kc0+3
    const int kr  = tid >> 1;           // 0..127
    const int kc0 = (tid & 1) * 4;
    // V staging: thread covers key vr (both halves), chunks vc0, vc0+1
    const int vr  = tid >> 2;           // 0..63
    const int vc0 = (tid & 3) * 2;

    __bf16* Pw = &Ps[w * 32 * 136];

    for (int pass = 0; pass < 2; ++pass) {
        const int qs  = pass ? 15 - pair : pair;
        const int qt0 = qs * 128;
        const int nt  = qs + 1;

        // Q fragments for both 16-row groups
        bf16x8_t qa[2], qb[2];
#pragma unroll
        for (int qf = 0; qf < 2; ++qf) {
            const __bf16* qrow = qg + (size_t)(qt0 + w * 32 + qf * 16 + lr) * C3;
            qa[qf] = *(const bf16x8_t*)&qrow[lk];
            qb[qf] = *(const bf16x8_t*)&qrow[32 + lk];
        }

        // tile-0 staged loads
        bf16x8_t kv[4], vv[4];
#pragma unroll
        for (int j = 0; j < 4; ++j)
            kv[j] = *(const bf16x8_t*)&kg[(size_t)kr * C3 + (kc0 + j) * 8];
#pragma unroll
        for (int hf = 0; hf < 2; ++hf)
#pragma unroll
            for (int u = 0; u < 2; ++u)
                vv[hf * 2 + u] = *(const bf16x8_t*)&vg[(size_t)(hf * 64 + vr) * C3 + (vc0 + u) * 8];

        f32x4_t o_acc[2][4];
#pragma unroll
        for (int qf = 0; qf < 2; ++qf)
#pragma unroll
            for (int i = 0; i < 4; ++i) o_acc[qf][i] = (f32x4_t){0.f, 0.f, 0.f, 0.f};
        float m_r[2] = {-3.0e38f, -3.0e38f};
        float l_r[2] = {0.f, 0.f};

        for (int t = 0; t < nt; ++t) {
            __syncthreads();   // prev tile reads done; staged regs valid

            // write staged tile to LDS
#pragma unroll
            for (int j = 0; j < 4; ++j)
                *(bf16x8_t*)&Ks[kr * 64 + (((kc0 + j) ^ (kr & 7)) << 3)] = kv[j];
#pragma unroll
            for (int hf = 0; hf < 2; ++hf)
#pragma unroll
                for (int u = 0; u < 2; ++u) {
                    const int c  = vc0 + u;
                    const int ks = vr ^ (c << 3);
#pragma unroll
                    for (int j = 0; j < 8; ++j)
                        Vt[hf][(c * 8 + j) * 72 + ks] = vv[hf * 2 + u][j];
                }

            __syncthreads();   // tile visible

            // prefetch next tile into regs (hides under compute)
            if (t + 1 < nt) {
                const size_t kb0 = (size_t)(t + 1) * 128;
#pragma unroll
                for (int j = 0; j < 4; ++j)
                    kv[j] = *(const bf16x8_t*)&kg[(kb0 + kr) * C3 + (kc0 + j) * 8];
#pragma unroll
                for (int hf = 0; hf < 2; ++hf)
#pragma unroll
                    for (int u = 0; u < 2; ++u)
                        vv[hf * 2 + u] = *(const bf16x8_t*)&vg[(kb0 + hf * 64 + vr) * C3 + (vc0 + u) * 8];
            }

            // --- S^T = K Q^T for both q-fragments, sharing K reads ---
            f32x4_t s0[8], s1[8];
#pragma unroll
            for (int c = 0; c < 8; ++c) {
                const int key = c * 16 + lr;
                const int sw  = (key & 7) << 3;
                bf16x8_t kfa = *(const bf16x8_t*)&Ks[key * 64 + (lk ^ sw)];
                bf16x8_t kfb = *(const bf16x8_t*)&Ks[key * 64 + ((32 + lk) ^ sw)];
                s0[c] = __builtin_amdgcn_mfma_f32_16x16x32_bf16(kfa, qa[0], (f32x4_t){0.f, 0.f, 0.f, 0.f}, 0, 0, 0);
                s0[c] = __builtin_amdgcn_mfma_f32_16x16x32_bf16(kfb, qb[0], s0[c], 0, 0, 0);
                s1[c] = __builtin_amdgcn_mfma_f32_16x16x32_bf16(kfa, qa[1], (f32x4_t){0.f, 0.f, 0.f, 0.f}, 0, 0, 0);
                s1[c] = __builtin_amdgcn_mfma_f32_16x16x32_bf16(kfb, qb[1], s1[c], 0, 0, 0);
            }

            // --- causal mask (diagonal supertile only) ---
            if (t == nt - 1) {
#pragma unroll
                for (int c = 0; c < 8; ++c)
#pragma unroll
                    for (int r = 0; r < 4; ++r) {
                        const int ko = c * 16 + lg * 4 + r;
                        if (ko > w * 32 + lr)      s0[c][r] = -1.0e30f;
                        if (ko > w * 32 + 16 + lr) s1[c][r] = -1.0e30f;
                    }
            }

            // --- online softmax + P write, per q-fragment ---
#pragma unroll
            for (int qf = 0; qf < 2; ++qf) {
                f32x4_t* s = qf ? s1 : s0;
                float pm = s[0][0];
#pragma unroll
                for (int c = 0; c < 8; ++c)
#pragma unroll
                    for (int r = 0; r < 4; ++r) pm = fmaxf(pm, s[c][r]);

                if (!__all(pm <= m_r[qf] + DEFER)) {
                    pm = fmaxf(pm, __shfl_xor(pm, 16));
                    pm = fmaxf(pm, __shfl_xor(pm, 32));
                    const float mn    = fmaxf(m_r[qf], pm);
                    const float alpha = exp2f((m_r[qf] - mn) * CE);
                    l_r[qf] *= alpha;
#pragma unroll
                    for (int dt = 0; dt < 4; ++dt)
#pragma unroll
                        for (int r = 0; r < 4; ++r) o_acc[qf][dt][r] *= alpha;
                    m_r[qf] = mn;
                }
                const float mce = m_r[qf] * CE;

                float rs = 0.f;
#pragma unroll
                for (int c = 0; c < 8; ++c) {
                    bf16x4_t pk;
#pragma unroll
                    for (int r = 0; r < 4; ++r) {
                        float pv = exp2f(fmaf(s[c][r], CE, -mce));
                        rs += pv;
                        pk[r] = (__bf16)pv;
                    }
                    *(bf16x4_t*)&Pw[(qf * 16 + lr) * 136 + c * 16 + lg * 4] = pk;
                }
                rs += __shfl_xor(rs, 16);
                rs += __shfl_xor(rs, 32);
                l_r[qf] += rs;
            }

            // --- O^T += V^T P^T, V-fragment reads shared across q-fragments ---
#pragma unroll
            for (int hf = 0; hf < 2; ++hf) {
                bf16x8_t pb0[2], pb1[2];
#pragma unroll
                for (int qf = 0; qf < 2; ++qf) {
                    pb0[qf] = *(const bf16x8_t*)&Pw[(qf * 16 + lr) * 136 + hf * 64 + lk];
                    pb1[qf] = *(const bf16x8_t*)&Pw[(qf * 16 + lr) * 136 + hf * 64 + 32 + lk];
                }
#pragma unroll
                for (int dt = 0; dt < 4; ++dt) {
                    const int d   = dt * 16 + lr;
                    const int sw2 = ((d >> 3) & 7) << 3;
                    bf16x8_t vb0 = *(const bf16x8_t*)&Vt[hf][d * 72 + (lk ^ sw2)];
                    bf16x8_t vb1 = *(const bf16x8_t*)&Vt[hf][d * 72 + ((32 + lk) ^ sw2)];
#pragma unroll
                    for (int qf = 0; qf < 2; ++qf) {
                        o_acc[qf][dt] = __builtin_amdgcn_mfma_f32_16x16x32_bf16(vb0, pb0[qf], o_acc[qf][dt], 0, 0, 0);
                        o_acc[qf][dt] = __builtin_amdgcn_mfma_f32_16x16x32_bf16(vb1, pb1[qf], o_acc[qf][dt], 0, 0, 0);
                    }
                }
            }
        }

        // --- epilogue ---
#pragma unroll
        for (int qf = 0; qf < 2; ++qf) {
            const float inv = 1.0f / l_r[qf];
            const int q = qt0 + w * 32 + qf * 16 + lr;
#pragma unroll
            for (int dt = 0; dt < 4; ++dt) {
                bf16x4_t ov;
#pragma unroll
                for (int r = 0; r < 4; ++r) ov[r] = (__bf16)(o_acc[qf][dt][r] * inv);
                *(bf16x4_t*)&y[(size_t)(b * T + q) * 1024 + h * 64 + dt * 16 + lg * 4] = ov;
            }
        }
    }
}

// ---------------- launch ----------------
extern "C" void kernel_launch(void* const* d_in, const int* in_sizes, int n_in,
                              void* d_out, int out_size, void* d_ws, size_t ws_size,
                              hipStream_t stream) {
    const float* x      = (const float*)d_in[0];
    const float* w_attn = (const float*)d_in[1];
    const float* w_proj = (const float*)d_in[2];
    float* out = (float*)d_out;

    char* ws = (char*)d_ws;
    __bf16* xb   = (__bf16*)(ws);                      // 8192*1024   = 16 MB
    __bf16* wab  = (__bf16*)(ws + 16777216);           // 3072*1024   = 6 MB
    __bf16* wpb  = (__bf16*)(ws + 23068672);           // 1024*1024   = 2 MB
    __bf16* qkvb = (__bf16*)(ws + 25165824);           // 8192*3072   = 48 MB
    __bf16* yb   = (__bf16*)(ws + 75497472);           // 8192*1024   = 16 MB

    f2bf_kernel<<<8192, 256, 0, stream>>>(x, xb, 8388608);
    f2bf_kernel<<<3072, 256, 0, stream>>>(w_attn, wab, 3145728);
    f2bf_kernel<<<1024, 256, 0, stream>>>(w_proj, wpb, 1048576);

    // qkv = x @ w_attn^T   [8192, 3072]
    gemm_bt<__bf16><<<dim3(24, 64), 256, 0, stream>>>(xb, wab, qkvb, 8192, 3072, 1024);

    // flash attention -> yb [8192, 1024]
    attn_kernel<<<512, 256, 0, stream>>>(qkvb, yb);

    // out = yb @ w_proj^T  [8192, 1024] fp32
    gemm_bt<float><<<dim3(8, 64), 256, 0, stream>>>(yb, wpb, out, 8192, 1024, 1024);
}

// Round 8
// 188.242 us; speedup vs baseline: 1.0969x; 1.0579x over previous
//
#include <hip/hip_runtime.h>
#include <hip/hip_bf16.h>

typedef __bf16 bf16x8_t __attribute__((ext_vector_type(8)));
typedef __bf16 bf16x4_t __attribute__((ext_vector_type(4)));
typedef float f32x4_t __attribute__((ext_vector_type(4)));

__device__ __forceinline__ void gload_lds16(const void* g, void* l) {
    __builtin_amdgcn_global_load_lds((const __attribute__((address_space(1))) void*)g,
                                     (__attribute__((address_space(3))) void*)l, 16, 0, 0);
}

// ---------------- fp32 -> bf16 conversion ----------------
__global__ void f2bf_kernel(const float* __restrict__ in, __bf16* __restrict__ out, int n) {
    int i = (blockIdx.x * blockDim.x + threadIdx.x) * 4;
    if (i >= n) return;
    float4 v = *(const float4*)(in + i);
    bf16x4_t o;
    o[0] = (__bf16)v.x; o[1] = (__bf16)v.y; o[2] = (__bf16)v.z; o[3] = (__bf16)v.w;
    *(bf16x4_t*)(out + i) = o;
}

// ---------------- GEMM1 (8-phase, from R5): qkv = x @ w_attn^T ----------------
// BM=128 BN=256 BK=64, 8 waves. Q/K columns (col<2048) -> Cqk [8192][2048].
// V columns (col>=2048) -> Vg[(b*16+h)][d][2048] TRANSPOSED (packed b64 stores).
__global__ __launch_bounds__(512, 2) void gemm1_8ph(const __bf16* __restrict__ A,
                                                    const __bf16* __restrict__ Bt,
                                                    __bf16* __restrict__ Cqk,
                                                    __bf16* __restrict__ Vg,
                                                    int M, int N, int K) {
    __shared__ __bf16 AsB[2][16 * 512];   // 128 rows x 64 cols per buf
    __shared__ __bf16 BsB[2][32 * 512];   // 256 rows x 64 cols per buf

    const int tid  = threadIdx.x;
    const int lane = tid & 63;
    const int wid  = tid >> 6;
    const int wm   = wid >> 2;      // 0..1 (M half)
    const int wn   = wid & 3;       // 0..3 (N quarter)

    const int nwg   = gridDim.x;
    const int ntile = N >> 8;
    int fl = blockIdx.x;
    fl = (fl & 7) * (nwg >> 3) + (fl >> 3);
    const int m0 = (fl / ntile) * 128;
    const int n0 = (fl % ntile) * 256;

    const int lr = lane & 15;
    const int lg = lane >> 4;
    const int cr = lg * 4;
    const int srow = lane >> 3;
    const int gcol = (((lane & 7) ^ srow) << 3);

    f32x4_t acc[4][4];
#pragma unroll
    for (int i = 0; i < 4; ++i)
#pragma unroll
        for (int j = 0; j < 4; ++j)
            acc[i][j] = (f32x4_t){0.f, 0.f, 0.f, 0.f};

    const int NT = K >> 6;

    auto stage = [&](int kt, int buf) {
        const __bf16* Ab = A + (size_t)m0 * K + kt * 64;
        const __bf16* Bb = Bt + (size_t)n0 * K + kt * 64;
        __bf16* Al = &AsB[buf][0];
        __bf16* Bl = &BsB[buf][0];
#pragma unroll
        for (int j = 0; j < 6; ++j) {
            int seg = wid * 6 + j;
            if (seg < 16) {
                gload_lds16(Ab + (size_t)(seg * 8 + srow) * K + gcol, Al + seg * 512);
            } else {
                int s2 = seg - 16;
                gload_lds16(Bb + (size_t)(s2 * 8 + srow) * K + gcol, Bl + s2 * 512);
            }
        }
    };

    stage(0, 0);

    for (int kt = 0; kt < NT; ++kt) {
        const int cur = kt & 1;
        const bool pf = (kt + 1 < NT);
        if (pf) stage(kt + 1, cur ^ 1);

        if (pf) asm volatile("s_waitcnt vmcnt(6)" ::: "memory");
        else    asm volatile("s_waitcnt vmcnt(0)" ::: "memory");
        __builtin_amdgcn_sched_barrier(0);
        __builtin_amdgcn_s_barrier();
        __builtin_amdgcn_sched_barrier(0);

        const __bf16* Al = &AsB[cur][0];
        const __bf16* Bl = &BsB[cur][0];

        bf16x8_t af[4][2];
#pragma unroll
        for (int mf = 0; mf < 4; ++mf)
#pragma unroll
            for (int kk = 0; kk < 2; ++kk) {
                const int row = wm * 64 + mf * 16 + lr;
                const int g   = kk * 4 + lg;
                af[mf][kk] = *(const bf16x8_t*)&Al[row * 64 + ((g ^ (row & 7)) << 3)];
            }

#pragma unroll
        for (int p = 0; p < 2; ++p) {
            bf16x8_t bfr[2][2];
#pragma unroll
            for (int nfp = 0; nfp < 2; ++nfp)
#pragma unroll
                for (int kk = 0; kk < 2; ++kk) {
                    const int row = wn * 64 + (p * 2 + nfp) * 16 + lr;
                    const int g   = kk * 4 + lg;
                    bfr[nfp][kk] = *(const bf16x8_t*)&Bl[row * 64 + ((g ^ (row & 7)) << 3)];
                }
            __builtin_amdgcn_s_setprio(1);
#pragma unroll
            for (int mf = 0; mf < 4; ++mf)
#pragma unroll
                for (int nfp = 0; nfp < 2; ++nfp) {
                    const int nf = p * 2 + nfp;
                    acc[mf][nf] = __builtin_amdgcn_mfma_f32_16x16x32_bf16(af[mf][0], bfr[nfp][0], acc[mf][nf], 0, 0, 0);
                    acc[mf][nf] = __builtin_amdgcn_mfma_f32_16x16x32_bf16(af[mf][1], bfr[nfp][1], acc[mf][nf], 0, 0, 0);
                }
            __builtin_amdgcn_s_setprio(0);
            __builtin_amdgcn_s_barrier();
        }
        __builtin_amdgcn_sched_barrier(0);
    }

    if (n0 < 2048) {
        // Q/K region: normal row-major store, ld=2048
#pragma unroll
        for (int mf = 0; mf < 4; ++mf)
#pragma unroll
            for (int nf = 0; nf < 4; ++nf)
#pragma unroll
                for (int r = 0; r < 4; ++r) {
                    int row = m0 + wm * 64 + mf * 16 + cr + r;
                    int col = n0 + wn * 64 + nf * 16 + lr;
                    Cqk[(size_t)row * 2048 + col] = (__bf16)acc[mf][nf][r];
                }
    } else {
        // V region: write TRANSPOSED into Vg[(b*16+h)*64+d][2048], packed b64
#pragma unroll
        for (int mf = 0; mf < 4; ++mf) {
            const int row0 = m0 + wm * 64 + mf * 16 + cr;   // 4 consecutive rows
            const int bb   = row0 >> 11;
            const int tt   = row0 & 2047;
#pragma unroll
            for (int nf = 0; nf < 4; ++nf) {
                const int c3 = n0 + wn * 64 + nf * 16 + lr - 2048;  // 0..1023
                const int hh = c3 >> 6, dd = c3 & 63;
                bf16x4_t pv;
#pragma unroll
                for (int r = 0; r < 4; ++r) pv[r] = (__bf16)acc[mf][nf][r];
                *(bf16x4_t*)&Vg[((size_t)(bb * 16 + hh) * 64 + dd) * 2048 + tt] = pv;
            }
        }
    }
}

// ---------------- bf16 GEMM (m97-style 128x128, proven): C = A * Bt^T ----------------
template <typename OutT>
__global__ __launch_bounds__(256) void gemm_bt(const __bf16* __restrict__ A,
                                               const __bf16* __restrict__ Bt,
                                               OutT* __restrict__ C,
                                               int M, int N, int K) {
    __shared__ __bf16 As[128 * 32];
    __shared__ __bf16 Bs[128 * 32];

    const int tid  = threadIdx.x;
    const int lane = tid & 63;
    const int wid  = tid >> 6;
    const int wm   = wid >> 1;
    const int wn   = wid & 1;

    const int nwg = gridDim.x * gridDim.y;
    int fl = blockIdx.y * gridDim.x + blockIdx.x;
    fl = (fl & 7) * (nwg >> 3) + (fl >> 3);
    const int m0 = (fl / gridDim.x) * 128;
    const int n0 = (fl % gridDim.x) * 128;

    const int lr = lane & 15;
    const int lk = (lane >> 4) * 8;
    const int cr = (lane >> 4) * 4;

    f32x4_t acc[4][4];
    for (int i = 0; i < 4; ++i)
        for (int j = 0; j < 4; ++j)
            acc[i][j] = (f32x4_t){0.f, 0.f, 0.f, 0.f};

    for (int k0 = 0; k0 < K; k0 += 32) {
        __syncthreads();
        for (int i = 0; i < 2; ++i) {
            int flat = i * 256 + tid;
            int row  = flat >> 2;
            int col  = (flat & 3) * 8;
            gload_lds16(&A[(size_t)(m0 + row) * K + k0 + col], &As[(size_t)(i * 256 + wid * 64) * 8]);
            gload_lds16(&Bt[(size_t)(n0 + row) * K + k0 + col], &Bs[(size_t)(i * 256 + wid * 64) * 8]);
        }
        __syncthreads();

        bf16x8_t af[4], bfr[4];
        for (int mf = 0; mf < 4; ++mf)
            af[mf] = *(const bf16x8_t*)&As[(wm * 64 + mf * 16 + lr) * 32 + lk];
        for (int nf = 0; nf < 4; ++nf)
            bfr[nf] = *(const bf16x8_t*)&Bs[(wn * 64 + nf * 16 + lr) * 32 + lk];
        for (int mf = 0; mf < 4; ++mf)
            for (int nf = 0; nf < 4; ++nf)
                acc[mf][nf] = __builtin_amdgcn_mfma_f32_16x16x32_bf16(af[mf], bfr[nf], acc[mf][nf], 0, 0, 0);
    }

    for (int mf = 0; mf < 4; ++mf)
        for (int nf = 0; nf < 4; ++nf)
            for (int r = 0; r < 4; ++r) {
                int row = m0 + wm * 64 + mf * 16 + cr + r;
                int col = n0 + wn * 64 + nf * 16 + lr;
                C[(size_t)row * N + col] = (OutT)acc[mf][nf][r];
            }
}

// ---------------- flash attention (causal), v6 ----------------
// v4 structure (8 waves x 16 q-rows, QBLK=128, KVBLK=128, proven 82us) with
// V staged from pre-transposed Vg: 2 coalesced b128 loads + 2 swizzled b128
// LDS writes (replaces 16 scalar transpose writes). Vt = [d(64)][key(128) swz].
__global__ __launch_bounds__(512, 4) void attn_kernel(const __bf16* __restrict__ qkv,  // [8192][2048] Q|K
                                                      const __bf16* __restrict__ Vg,   // [(b*16+h)*64+d][2048]
                                                      __bf16* __restrict__ y) {
    const int T = 2048, LD = 2048;
    const int orig = blockIdx.x;
    const int bidx = ((orig & 7) << 6) + (orig >> 3);   // XCD swizzle (512 % 8 == 0)
    const int pair = bidx & 7;
    const int h    = (bidx >> 3) & 15;
    const int b    = bidx >> 7;

    __shared__ __bf16 Ks[128 * 64];      // [key][chunk-swizzled dims]
    __shared__ __bf16 Vt[64 * 128];      // [d][key-slot swizzled]
    __shared__ __bf16 Ps[8 * 16 * 136];  // per-wave [q(16)][key(128)+pad]

    const int tid  = threadIdx.x;
    const int lane = tid & 63;
    const int w    = tid >> 6;
    const int lr   = lane & 15;
    const int lg   = lane >> 4;
    const int lk   = lg * 8;

    const __bf16* qg  = qkv + (size_t)b * T * LD + h * 64;
    const __bf16* kg  = qg + 1024;
    const __bf16* Vgb = Vg + (size_t)(b * 16 + h) * 64 * 2048;

    const float CE    = 0.125f * 1.44269504f;
    const float DEFER = 44.0f;

    // K staging map (rows r0, 64+r0; chunk kcol; swizzled slot)
    const int r0    = tid >> 3;
    const int kcol  = (tid & 7) * 8;
    const int kslot = ((tid & 7) ^ (r0 & 7)) << 3;
    // V staging map: dim vd (0..63), chunks vc0 and vc0+8
    const int vd  = tid >> 3;
    const int vc0 = tid & 7;

    __bf16* Pw = &Ps[w * 16 * 136];

    for (int pass = 0; pass < 2; ++pass) {
        const int qs  = pass ? 15 - pair : pair;
        const int qt0 = qs * 128;
        const int nt  = qs + 1;

        bf16x8_t qf0, qf1;
        {
            const __bf16* qrow = qg + (size_t)(qt0 + w * 16 + lr) * LD;
            qf0 = *(const bf16x8_t*)&qrow[lk];
            qf1 = *(const bf16x8_t*)&qrow[32 + lk];
        }

        // tile-0 staged loads
        bf16x8_t ka = *(const bf16x8_t*)&kg[(size_t)r0 * LD + kcol];
        bf16x8_t kb = *(const bf16x8_t*)&kg[(size_t)(64 + r0) * LD + kcol];
        bf16x8_t va = *(const bf16x8_t*)&Vgb[(size_t)vd * 2048 + vc0 * 8];
        bf16x8_t vb = *(const bf16x8_t*)&Vgb[(size_t)vd * 2048 + (vc0 + 8) * 8];

        f32x4_t o_acc[4];
#pragma unroll
        for (int i = 0; i < 4; ++i) o_acc[i] = (f32x4_t){0.f, 0.f, 0.f, 0.f};
        float m_r = -3.0e38f, l_r = 0.f;

        for (int t = 0; t < nt; ++t) {
            __syncthreads();   // prev tile reads done; staged regs valid

            // write staged tile to LDS
            *(bf16x8_t*)&Ks[r0 * 64 + kslot] = ka;
            *(bf16x8_t*)&Ks[(64 + r0) * 64 + kslot] = kb;
            *(bf16x8_t*)&Vt[vd * 128 + ((vc0 ^ (vd & 7)) << 3)] = va;
            *(bf16x8_t*)&Vt[vd * 128 + (((vc0 + 8) ^ (vd & 7)) << 3)] = vb;

            __syncthreads();   // tile visible

            // prefetch next tile into regs (hides under compute)
            if (t + 1 < nt) {
                const size_t kb0 = (size_t)(t + 1) * 128;
                ka = *(const bf16x8_t*)&kg[(kb0 + r0) * LD + kcol];
                kb = *(const bf16x8_t*)&kg[(kb0 + 64 + r0) * LD + kcol];
                va = *(const bf16x8_t*)&Vgb[(size_t)vd * 2048 + kb0 + vc0 * 8];
                vb = *(const bf16x8_t*)&Vgb[(size_t)vd * 2048 + kb0 + (vc0 + 8) * 8];
            }

            // --- S^T = K Q^T ---
            f32x4_t s[8];
#pragma unroll
            for (int c = 0; c < 8; ++c) {
                const int key = c * 16 + lr;
                const int sw  = (key & 7) << 3;
                bf16x8_t kfa = *(const bf16x8_t*)&Ks[key * 64 + (lk ^ sw)];
                bf16x8_t kfb = *(const bf16x8_t*)&Ks[key * 64 + ((32 + lk) ^ sw)];
                s[c] = __builtin_amdgcn_mfma_f32_16x16x32_bf16(kfa, qf0, (f32x4_t){0.f, 0.f, 0.f, 0.f}, 0, 0, 0);
                s[c] = __builtin_amdgcn_mfma_f32_16x16x32_bf16(kfb, qf1, s[c], 0, 0, 0);
            }

            // --- causal mask (diagonal supertile only) ---
            if (t == nt - 1) {
                const int ql = w * 16 + lr;
#pragma unroll
                for (int c = 0; c < 8; ++c)
#pragma unroll
                    for (int r = 0; r < 4; ++r)
                        if (c * 16 + lg * 4 + r > ql) s[c][r] = -1.0e30f;
            }

            // --- online softmax with defer-max ---
            float pm = s[0][0];
#pragma unroll
            for (int c = 0; c < 8; ++c)
#pragma unroll
                for (int r = 0; r < 4; ++r) pm = fmaxf(pm, s[c][r]);

            if (!__all(pm <= m_r + DEFER)) {
                pm = fmaxf(pm, __shfl_xor(pm, 16));
                pm = fmaxf(pm, __shfl_xor(pm, 32));
                const float mn    = fmaxf(m_r, pm);
                const float alpha = exp2f((m_r - mn) * CE);
                l_r *= alpha;
#pragma unroll
                for (int dt = 0; dt < 4; ++dt)
#pragma unroll
                    for (int r = 0; r < 4; ++r) o_acc[dt][r] *= alpha;
                m_r = mn;
            }
            const float mce = m_r * CE;

            float rs = 0.f;
#pragma unroll
            for (int c = 0; c < 8; ++c) {
                bf16x4_t pk;
#pragma unroll
                for (int r = 0; r < 4; ++r) {
                    float pv = exp2f(fmaf(s[c][r], CE, -mce));
                    rs += pv;
                    pk[r] = (__bf16)pv;
                }
                *(bf16x4_t*)&Pw[lr * 136 + c * 16 + lg * 4] = pk;
            }
            rs += __shfl_xor(rs, 16);
            rs += __shfl_xor(rs, 32);
            l_r += rs;

            // --- O^T += V^T P^T ---
#pragma unroll
            for (int hf = 0; hf < 2; ++hf) {
                bf16x8_t pb0 = *(const bf16x8_t*)&Pw[lr * 136 + hf * 64 + lk];
                bf16x8_t pb1 = *(const bf16x8_t*)&Pw[lr * 136 + hf * 64 + 32 + lk];
#pragma unroll
                for (int dt = 0; dt < 4; ++dt) {
                    const int d = dt * 16 + lr;
                    bf16x8_t vb0 = *(const bf16x8_t*)&Vt[d * 128 + (((hf * 8 + lg) ^ (d & 7)) << 3)];
                    bf16x8_t vb1 = *(const bf16x8_t*)&Vt[d * 128 + (((hf * 8 + 4 + lg) ^ (d & 7)) << 3)];
                    o_acc[dt] = __builtin_amdgcn_mfma_f32_16x16x32_bf16(vb0, pb0, o_acc[dt], 0, 0, 0);
                    o_acc[dt] = __builtin_amdgcn_mfma_f32_16x16x32_bf16(vb1, pb1, o_acc[dt], 0, 0, 0);
                }
            }
        }

        const float inv = 1.0f / l_r;
        const int q = qt0 + w * 16 + lr;
#pragma unroll
        for (int dt = 0; dt < 4; ++dt) {
            bf16x4_t ov;
#pragma unroll
            for (int r = 0; r < 4; ++r) ov[r] = (__bf16)(o_acc[dt][r] * inv);
            *(bf16x4_t*)&y[(size_t)(b * T + q) * 1024 + h * 64 + dt * 16 + lg * 4] = ov;
        }
    }
}

// ---------------- launch ----------------
extern "C" void kernel_launch(void* const* d_in, const int* in_sizes, int n_in,
                              void* d_out, int out_size, void* d_ws, size_t ws_size,
                              hipStream_t stream) {
    const float* x      = (const float*)d_in[0];
    const float* w_attn = (const float*)d_in[1];
    const float* w_proj = (const float*)d_in[2];
    float* out = (float*)d_out;

    char* ws = (char*)d_ws;
    __bf16* xb   = (__bf16*)(ws);                      // 8192*1024      = 16 MB
    __bf16* wab  = (__bf16*)(ws + 16777216);           // 3072*1024      = 6 MB
    __bf16* wpb  = (__bf16*)(ws + 23068672);           // 1024*1024      = 2 MB
    __bf16* qkvb = (__bf16*)(ws + 25165824);           // 8192*2048 Q|K  = 32 MB
    __bf16* yb   = (__bf16*)(ws + 58720256);           // 8192*1024      = 16 MB
    __bf16* Vg   = (__bf16*)(ws + 75497472);           // 64*64*2048     = 16 MB

    f2bf_kernel<<<8192, 256, 0, stream>>>(x, xb, 8388608);
    f2bf_kernel<<<3072, 256, 0, stream>>>(w_attn, wab, 3145728);
    f2bf_kernel<<<1024, 256, 0, stream>>>(w_proj, wpb, 1048576);

    // qkv: Q/K -> qkvb [8192][2048]; V -> Vg transposed
    gemm1_8ph<<<768, 512, 0, stream>>>(xb, wab, qkvb, Vg, 8192, 3072, 1024);

    // flash attention -> yb [8192, 1024]
    attn_kernel<<<512, 512, 0, stream>>>(qkvb, Vg, yb);

    // out = yb @ w_proj^T  [8192, 1024] fp32
    gemm_bt<float><<<dim3(8, 64), 256, 0, stream>>>(yb, wpb, out, 8192, 1024, 1024);
}

// Round 9
// 181.257 us; speedup vs baseline: 1.1391x; 1.0385x over previous
//
#include <hip/hip_runtime.h>
#include <hip/hip_bf16.h>

typedef __bf16 bf16x8_t __attribute__((ext_vector_type(8)));
typedef __bf16 bf16x4_t __attribute__((ext_vector_type(4)));
typedef float f32x4_t __attribute__((ext_vector_type(4)));

__device__ __forceinline__ void gload_lds16(const void* g, void* l) {
    __builtin_amdgcn_global_load_lds((const __attribute__((address_space(1))) void*)g,
                                     (__attribute__((address_space(3))) void*)l, 16, 0, 0);
}

// ---------------- fused fp32 -> bf16 conversion (x, w_attn, w_proj) ----------------
__global__ void f2bf3_kernel(const float* __restrict__ x, const float* __restrict__ wa,
                             const float* __restrict__ wp, __bf16* __restrict__ xb,
                             __bf16* __restrict__ wab, __bf16* __restrict__ wpb) {
    int i = blockIdx.x * blockDim.x + threadIdx.x;   // float4 index, total 3145728
    const float* in; __bf16* out; int off;
    if (i < 2097152)      { in = x;  out = xb;  off = i; }
    else if (i < 2883584) { in = wa; out = wab; off = i - 2097152; }
    else                  { in = wp; out = wpb; off = i - 2883584; }
    float4 v = *(const float4*)(in + off * 4);
    bf16x4_t o;
    o[0] = (__bf16)v.x; o[1] = (__bf16)v.y; o[2] = (__bf16)v.z; o[3] = (__bf16)v.w;
    *(bf16x4_t*)(out + off * 4) = o;
}

// ---------------- GEMM1: m201-style 256x256 8-phase, BK=64 ----------------
// qkv = x @ w_attn^T. Q/K cols -> Cqk [8192][2048]; V cols -> Vg transposed.
// 8 waves (2M x 4N), per-wave 128x64 output. 128 KB dbuf LDS.
// Ledger: ph1,2 stage A(t+1); ph3,4 B(t+2); ph5,6 A(t+2); ph7,8 B(t+3).
// vmcnt(4) at ph4/ph8 (2 halves x 2 loads in flight); vmcnt(0) last iter.
__global__ __launch_bounds__(512, 2) void gemm1_m201(const __bf16* __restrict__ A,
                                                     const __bf16* __restrict__ Bt,
                                                     __bf16* __restrict__ Cqk,
                                                     __bf16* __restrict__ Vg,
                                                     int M, int N, int K) {
    __shared__ __bf16 As[2][256 * 64];
    __shared__ __bf16 Bs[2][256 * 64];

    const int tid  = threadIdx.x;
    const int lane = tid & 63;
    const int wid  = tid >> 6;
    const int wm   = wid >> 2;      // 0..1
    const int wn   = wid & 3;       // 0..3

    // XCD swizzle (384 % 8 == 0 -> bijective)
    int fl = blockIdx.x;
    fl = (fl & 7) * (gridDim.x >> 3) + (fl >> 3);
    const int m0 = (fl / 12) * 256;
    const int n0 = (fl % 12) * 256;

    const int lr = lane & 15;
    const int lg = lane >> 4;
    const int cr = lg * 4;
    const int srow = lane >> 3;
    const int gcol = (((lane & 7) ^ srow) << 3);

    f32x4_t acc[8][4];
#pragma unroll
    for (int i = 0; i < 8; ++i)
#pragma unroll
        for (int j = 0; j < 4; ++j)
            acc[i][j] = (f32x4_t){0.f, 0.f, 0.f, 0.f};

    const int NT = K >> 6;       // 16
    const int NI = NT >> 1;      // 8

    bf16x8_t af[4][2], bf0[2][2], bf1[2][2];

    // stage one half (A or B) of tile kt into buf: this wave's 2 segments
    auto stA = [&](int kt, int buf, int half) {
        const __bf16* Ab = A + (size_t)m0 * K + (size_t)kt * 64;
        const int s0 = half * 16 + wid, s1 = s0 + 8;
        gload_lds16(Ab + (size_t)(s0 * 8 + srow) * K + gcol, &As[buf][s0 * 512]);
        gload_lds16(Ab + (size_t)(s1 * 8 + srow) * K + gcol, &As[buf][s1 * 512]);
    };
    auto stB = [&](int kt, int buf, int half) {
        const __bf16* Bb = Bt + (size_t)n0 * K + (size_t)kt * 64;
        const int s0 = half * 16 + wid, s1 = s0 + 8;
        gload_lds16(Bb + (size_t)(s0 * 8 + srow) * K + gcol, &Bs[buf][s0 * 512]);
        gload_lds16(Bb + (size_t)(s1 * 8 + srow) * K + gcol, &Bs[buf][s1 * 512]);
    };
    auto dsA = [&](const __bf16* Ab, int mfh) {
#pragma unroll
        for (int mf = 0; mf < 4; ++mf)
#pragma unroll
            for (int kk = 0; kk < 2; ++kk) {
                const int row = wm * 128 + (mfh * 4 + mf) * 16 + lr;
                const int g   = kk * 4 + lg;
                af[mf][kk] = *(const bf16x8_t*)&Ab[row * 64 + ((g ^ (row & 7)) << 3)];
            }
    };
    auto dsB = [&](const __bf16* Bb, int nfh, bf16x8_t (&dst)[2][2]) {
#pragma unroll
        for (int nfp = 0; nfp < 2; ++nfp)
#pragma unroll
            for (int kk = 0; kk < 2; ++kk) {
                const int row = wn * 64 + (nfh * 2 + nfp) * 16 + lr;
                const int g   = kk * 4 + lg;
                dst[nfp][kk] = *(const bf16x8_t*)&Bb[row * 64 + ((g ^ (row & 7)) << 3)];
            }
    };
    auto MF = [&](int mfh, bf16x8_t (&bfr)[2][2], int nfh) {
        __builtin_amdgcn_s_setprio(1);
#pragma unroll
        for (int mf = 0; mf < 4; ++mf)
#pragma unroll
            for (int nfp = 0; nfp < 2; ++nfp) {
                const int ai = mfh * 4 + mf, bi = nfh * 2 + nfp;
                acc[ai][bi] = __builtin_amdgcn_mfma_f32_16x16x32_bf16(af[mf][0], bfr[nfp][0], acc[ai][bi], 0, 0, 0);
                acc[ai][bi] = __builtin_amdgcn_mfma_f32_16x16x32_bf16(af[mf][1], bfr[nfp][1], acc[ai][bi], 0, 0, 0);
            }
        __builtin_amdgcn_s_setprio(0);
    };

#define BAR() __builtin_amdgcn_s_barrier()
#define LGK0() asm volatile("s_waitcnt lgkmcnt(0)" ::: "memory")

    // prologue: tile 0 fully + B(1); vmcnt(4) leaves B(1) in flight
    stA(0, 0, 0); stA(0, 0, 1); stB(0, 0, 0); stB(0, 0, 1);
    stB(1, 1, 0); stB(1, 1, 1);
    asm volatile("s_waitcnt vmcnt(4)" ::: "memory");
    BAR();

    for (int it = 0; it < NI; ++it) {
        const int t1 = 2 * it + 1, t2 = 2 * it + 2, t3 = 2 * it + 3;
        const bool lastit = (it == NI - 1);

        // ph1: read A0,B0 of even tile; stage A-lo(t1)
        dsA(As[0], 0); dsB(Bs[0], 0, bf0);
        stA(t1, 1, 0);
        BAR(); LGK0();
        MF(0, bf0, 0);
        BAR();

        // ph2: read B1; stage A-hi(t1)
        dsB(Bs[0], 1, bf1);
        stA(t1, 1, 1);
        BAR(); LGK0();
        MF(0, bf1, 1);
        BAR();

        // ph3: read A1; stage B-lo(t2)
        dsA(As[0], 1);
        if (!lastit) stB(t2, 0, 0);
        BAR(); LGK0();
        MF(1, bf0, 0);
        BAR();

        // ph4: stage B-hi(t2); vmcnt -> A(t1),B(t1) landed
        if (!lastit) stB(t2, 0, 1);
        if (lastit) asm volatile("s_waitcnt vmcnt(0)" ::: "memory");
        else        asm volatile("s_waitcnt vmcnt(4)" ::: "memory");
        BAR();
        MF(1, bf1, 1);
        BAR();

        // ph5: read A0,B0 of odd tile; stage A-lo(t2)
        dsA(As[1], 0); dsB(Bs[1], 0, bf0);
        if (!lastit) stA(t2, 0, 0);
        BAR(); LGK0();
        MF(0, bf0, 0);
        BAR();

        // ph6: read B1; stage A-hi(t2)
        dsB(Bs[1], 1, bf1);
        if (!lastit) stA(t2, 0, 1);
        BAR(); LGK0();
        MF(0, bf1, 1);
        BAR();

        // ph7: read A1; stage B-lo(t3)
        dsA(As[1], 1);
        if (!lastit) stB(t3, 1, 0);
        BAR(); LGK0();
        MF(1, bf0, 0);
        BAR();

        // ph8: stage B-hi(t3); vmcnt -> t2 fully landed
        if (!lastit) stB(t3, 1, 1);
        if (lastit) asm volatile("s_waitcnt vmcnt(0)" ::: "memory");
        else        asm volatile("s_waitcnt vmcnt(4)" ::: "memory");
        BAR();
        MF(1, bf1, 1);
        BAR();
    }
#undef BAR
#undef LGK0

    if (n0 < 2048) {
#pragma unroll
        for (int mf = 0; mf < 8; ++mf)
#pragma unroll
            for (int nf = 0; nf < 4; ++nf)
#pragma unroll
                for (int r = 0; r < 4; ++r) {
                    int row = m0 + wm * 128 + mf * 16 + cr + r;
                    int col = n0 + wn * 64 + nf * 16 + lr;
                    Cqk[(size_t)row * 2048 + col] = (__bf16)acc[mf][nf][r];
                }
    } else {
        // V region: write TRANSPOSED into Vg[(b*16+h)*64+d][2048], packed b64
#pragma unroll
        for (int mf = 0; mf < 8; ++mf) {
            const int row0 = m0 + wm * 128 + mf * 16 + cr;
            const int bb   = row0 >> 11;
            const int tt   = row0 & 2047;
#pragma unroll
            for (int nf = 0; nf < 4; ++nf) {
                const int c3 = n0 + wn * 64 + nf * 16 + lr - 2048;
                const int hh = c3 >> 6, dd = c3 & 63;
                bf16x4_t pv;
#pragma unroll
                for (int r = 0; r < 4; ++r) pv[r] = (__bf16)acc[mf][nf][r];
                *(bf16x4_t*)&Vg[((size_t)(bb * 16 + hh) * 64 + dd) * 2048 + tt] = pv;
            }
        }
    }
}

// ---------------- bf16 GEMM (m97-style 128x128, proven): C = A * Bt^T ----------------
template <typename OutT>
__global__ __launch_bounds__(256) void gemm_bt(const __bf16* __restrict__ A,
                                               const __bf16* __restrict__ Bt,
                                               OutT* __restrict__ C,
                                               int M, int N, int K) {
    __shared__ __bf16 As[128 * 32];
    __shared__ __bf16 Bs[128 * 32];

    const int tid  = threadIdx.x;
    const int lane = tid & 63;
    const int wid  = tid >> 6;
    const int wm   = wid >> 1;
    const int wn   = wid & 1;

    const int nwg = gridDim.x * gridDim.y;
    int fl = blockIdx.y * gridDim.x + blockIdx.x;
    fl = (fl & 7) * (nwg >> 3) + (fl >> 3);
    const int m0 = (fl / gridDim.x) * 128;
    const int n0 = (fl % gridDim.x) * 128;

    const int lr = lane & 15;
    const int lk = (lane >> 4) * 8;
    const int cr = (lane >> 4) * 4;

    f32x4_t acc[4][4];
    for (int i = 0; i < 4; ++i)
        for (int j = 0; j < 4; ++j)
            acc[i][j] = (f32x4_t){0.f, 0.f, 0.f, 0.f};

    for (int k0 = 0; k0 < K; k0 += 32) {
        __syncthreads();
        for (int i = 0; i < 2; ++i) {
            int flat = i * 256 + tid;
            int row  = flat >> 2;
            int col  = (flat & 3) * 8;
            gload_lds16(&A[(size_t)(m0 + row) * K + k0 + col], &As[(size_t)(i * 256 + wid * 64) * 8]);
            gload_lds16(&Bt[(size_t)(n0 + row) * K + k0 + col], &Bs[(size_t)(i * 256 + wid * 64) * 8]);
        }
        __syncthreads();

        bf16x8_t af[4], bfr[4];
        for (int mf = 0; mf < 4; ++mf)
            af[mf] = *(const bf16x8_t*)&As[(wm * 64 + mf * 16 + lr) * 32 + lk];
        for (int nf = 0; nf < 4; ++nf)
            bfr[nf] = *(const bf16x8_t*)&Bs[(wn * 64 + nf * 16 + lr) * 32 + lk];
        for (int mf = 0; mf < 4; ++mf)
            for (int nf = 0; nf < 4; ++nf)
                acc[mf][nf] = __builtin_amdgcn_mfma_f32_16x16x32_bf16(af[mf], bfr[nf], acc[mf][nf], 0, 0, 0);
    }

    for (int mf = 0; mf < 4; ++mf)
        for (int nf = 0; nf < 4; ++nf)
            for (int r = 0; r < 4; ++r) {
                int row = m0 + wm * 64 + mf * 16 + cr + r;
                int col = n0 + wn * 64 + nf * 16 + lr;
                C[(size_t)row * N + col] = (OutT)acc[mf][nf][r];
            }
}

// ---------------- flash attention (causal), v6 + setprio ----------------
__global__ __launch_bounds__(512, 4) void attn_kernel(const __bf16* __restrict__ qkv,  // [8192][2048] Q|K
                                                      const __bf16* __restrict__ Vg,   // [(b*16+h)*64+d][2048]
                                                      __bf16* __restrict__ y) {
    const int T = 2048, LD = 2048;
    const int orig = blockIdx.x;
    const int bidx = ((orig & 7) << 6) + (orig >> 3);   // XCD swizzle
    const int pair = bidx & 7;
    const int h    = (bidx >> 3) & 15;
    const int b    = bidx >> 7;

    __shared__ __bf16 Ks[128 * 64];
    __shared__ __bf16 Vt[64 * 128];
    __shared__ __bf16 Ps[8 * 16 * 136];

    const int tid  = threadIdx.x;
    const int lane = tid & 63;
    const int w    = tid >> 6;
    const int lr   = lane & 15;
    const int lg   = lane >> 4;
    const int lk   = lg * 8;

    const __bf16* qg  = qkv + (size_t)b * T * LD + h * 64;
    const __bf16* kg  = qg + 1024;
    const __bf16* Vgb = Vg + (size_t)(b * 16 + h) * 64 * 2048;

    const float CE    = 0.125f * 1.44269504f;
    const float DEFER = 44.0f;

    const int r0    = tid >> 3;
    const int kcol  = (tid & 7) * 8;
    const int kslot = ((tid & 7) ^ (r0 & 7)) << 3;
    const int vd  = tid >> 3;
    const int vc0 = tid & 7;

    __bf16* Pw = &Ps[w * 16 * 136];

    for (int pass = 0; pass < 2; ++pass) {
        const int qs  = pass ? 15 - pair : pair;
        const int qt0 = qs * 128;
        const int nt  = qs + 1;

        bf16x8_t qf0, qf1;
        {
            const __bf16* qrow = qg + (size_t)(qt0 + w * 16 + lr) * LD;
            qf0 = *(const bf16x8_t*)&qrow[lk];
            qf1 = *(const bf16x8_t*)&qrow[32 + lk];
        }

        bf16x8_t ka = *(const bf16x8_t*)&kg[(size_t)r0 * LD + kcol];
        bf16x8_t kb = *(const bf16x8_t*)&kg[(size_t)(64 + r0) * LD + kcol];
        bf16x8_t va = *(const bf16x8_t*)&Vgb[(size_t)vd * 2048 + vc0 * 8];
        bf16x8_t vb = *(const bf16x8_t*)&Vgb[(size_t)vd * 2048 + (vc0 + 8) * 8];

        f32x4_t o_acc[4];
#pragma unroll
        for (int i = 0; i < 4; ++i) o_acc[i] = (f32x4_t){0.f, 0.f, 0.f, 0.f};
        float m_r = -3.0e38f, l_r = 0.f;

        for (int t = 0; t < nt; ++t) {
            __syncthreads();

            *(bf16x8_t*)&Ks[r0 * 64 + kslot] = ka;
            *(bf16x8_t*)&Ks[(64 + r0) * 64 + kslot] = kb;
            *(bf16x8_t*)&Vt[vd * 128 + ((vc0 ^ (vd & 7)) << 3)] = va;
            *(bf16x8_t*)&Vt[vd * 128 + (((vc0 + 8) ^ (vd & 7)) << 3)] = vb;

            __syncthreads();

            if (t + 1 < nt) {
                const size_t kb0 = (size_t)(t + 1) * 128;
                ka = *(const bf16x8_t*)&kg[(kb0 + r0) * LD + kcol];
                kb = *(const bf16x8_t*)&kg[(kb0 + 64 + r0) * LD + kcol];
                va = *(const bf16x8_t*)&Vgb[(size_t)vd * 2048 + kb0 + vc0 * 8];
                vb = *(const bf16x8_t*)&Vgb[(size_t)vd * 2048 + kb0 + (vc0 + 8) * 8];
            }

            // --- S^T = K Q^T ---
            f32x4_t s[8];
            __builtin_amdgcn_s_setprio(1);
#pragma unroll
            for (int c = 0; c < 8; ++c) {
                const int key = c * 16 + lr;
                const int sw  = (key & 7) << 3;
                bf16x8_t kfa = *(const bf16x8_t*)&Ks[key * 64 + (lk ^ sw)];
                bf16x8_t kfb = *(const bf16x8_t*)&Ks[key * 64 + ((32 + lk) ^ sw)];
                s[c] = __builtin_amdgcn_mfma_f32_16x16x32_bf16(kfa, qf0, (f32x4_t){0.f, 0.f, 0.f, 0.f}, 0, 0, 0);
                s[c] = __builtin_amdgcn_mfma_f32_16x16x32_bf16(kfb, qf1, s[c], 0, 0, 0);
            }
            __builtin_amdgcn_s_setprio(0);

            if (t == nt - 1) {
                const int ql = w * 16 + lr;
#pragma unroll
                for (int c = 0; c < 8; ++c)
#pragma unroll
                    for (int r = 0; r < 4; ++r)
                        if (c * 16 + lg * 4 + r > ql) s[c][r] = -1.0e30f;
            }

            float pm = s[0][0];
#pragma unroll
            for (int c = 0; c < 8; ++c)
#pragma unroll
                for (int r = 0; r < 4; ++r) pm = fmaxf(pm, s[c][r]);

            if (!__all(pm <= m_r + DEFER)) {
                pm = fmaxf(pm, __shfl_xor(pm, 16));
                pm = fmaxf(pm, __shfl_xor(pm, 32));
                const float mn    = fmaxf(m_r, pm);
                const float alpha = exp2f((m_r - mn) * CE);
                l_r *= alpha;
#pragma unroll
                for (int dt = 0; dt < 4; ++dt)
#pragma unroll
                    for (int r = 0; r < 4; ++r) o_acc[dt][r] *= alpha;
                m_r = mn;
            }
            const float mce = m_r * CE;

            float rs = 0.f;
#pragma unroll
            for (int c = 0; c < 8; ++c) {
                bf16x4_t pk;
#pragma unroll
                for (int r = 0; r < 4; ++r) {
                    float pv = exp2f(fmaf(s[c][r], CE, -mce));
                    rs += pv;
                    pk[r] = (__bf16)pv;
                }
                *(bf16x4_t*)&Pw[lr * 136 + c * 16 + lg * 4] = pk;
            }
            rs += __shfl_xor(rs, 16);
            rs += __shfl_xor(rs, 32);
            l_r += rs;

            // --- O^T += V^T P^T ---
            __builtin_amdgcn_s_setprio(1);
#pragma unroll
            for (int hf = 0; hf < 2; ++hf) {
                bf16x8_t pb0 = *(const bf16x8_t*)&Pw[lr * 136 + hf * 64 + lk];
                bf16x8_t pb1 = *(const bf16x8_t*)&Pw[lr * 136 + hf * 64 + 32 + lk];
#pragma unroll
                for (int dt = 0; dt < 4; ++dt) {
                    const int d = dt * 16 + lr;
                    bf16x8_t vb0 = *(const bf16x8_t*)&Vt[d * 128 + (((hf * 8 + lg) ^ (d & 7)) << 3)];
                    bf16x8_t vb1 = *(const bf16x8_t*)&Vt[d * 128 + (((hf * 8 + 4 + lg) ^ (d & 7)) << 3)];
                    o_acc[dt] = __builtin_amdgcn_mfma_f32_16x16x32_bf16(vb0, pb0, o_acc[dt], 0, 0, 0);
                    o_acc[dt] = __builtin_amdgcn_mfma_f32_16x16x32_bf16(vb1, pb1, o_acc[dt], 0, 0, 0);
                }
            }
            __builtin_amdgcn_s_setprio(0);
        }

        const float inv = 1.0f / l_r;
        const int q = qt0 + w * 16 + lr;
#pragma unroll
        for (int dt = 0; dt < 4; ++dt) {
            bf16x4_t ov;
#pragma unroll
            for (int r = 0; r < 4; ++r) ov[r] = (__bf16)(o_acc[dt][r] * inv);
            *(bf16x4_t*)&y[(size_t)(b * T + q) * 1024 + h * 64 + dt * 16 + lg * 4] = ov;
        }
    }
}

// ---------------- launch ----------------
extern "C" void kernel_launch(void* const* d_in, const int* in_sizes, int n_in,
                              void* d_out, int out_size, void* d_ws, size_t ws_size,
                              hipStream_t stream) {
    const float* x      = (const float*)d_in[0];
    const float* w_attn = (const float*)d_in[1];
    const float* w_proj = (const float*)d_in[2];
    float* out = (float*)d_out;

    char* ws = (char*)d_ws;
    __bf16* xb   = (__bf16*)(ws);                      // 8192*1024      = 16 MB
    __bf16* wab  = (__bf16*)(ws + 16777216);           // 3072*1024      = 6 MB
    __bf16* wpb  = (__bf16*)(ws + 23068672);           // 1024*1024      = 2 MB
    __bf16* qkvb = (__bf16*)(ws + 25165824);           // 8192*2048 Q|K  = 32 MB
    __bf16* yb   = (__bf16*)(ws + 58720256);           // 8192*1024      = 16 MB
    __bf16* Vg   = (__bf16*)(ws + 75497472);           // 64*64*2048     = 16 MB

    f2bf3_kernel<<<12288, 256, 0, stream>>>(x, w_attn, w_proj, xb, wab, wpb);

    // qkv: Q/K -> qkvb [8192][2048]; V -> Vg transposed  (256x256 8-phase)
    gemm1_m201<<<384, 512, 0, stream>>>(xb, wab, qkvb, Vg, 8192, 3072, 1024);

    // flash attention -> yb [8192, 1024]
    attn_kernel<<<512, 512, 0, stream>>>(qkvb, Vg, yb);

    // out = yb @ w_proj^T  [8192, 1024] fp32
    gemm_bt<float><<<dim3(8, 64), 256, 0, stream>>>(yb, wpb, out, 8192, 1024, 1024);
}

// Round 10
// 177.797 us; speedup vs baseline: 1.1613x; 1.0195x over previous
//
#include <hip/hip_runtime.h>
#include <hip/hip_bf16.h>

typedef __bf16 bf16x8_t __attribute__((ext_vector_type(8)));
typedef __bf16 bf16x4_t __attribute__((ext_vector_type(4)));
typedef float f32x4_t __attribute__((ext_vector_type(4)));
typedef float f32x16_t __attribute__((ext_vector_type(16)));

__device__ __forceinline__ void gload_lds16(const void* g, void* l) {
    __builtin_amdgcn_global_load_lds((const __attribute__((address_space(1))) void*)g,
                                     (__attribute__((address_space(3))) void*)l, 16, 0, 0);
}

__device__ __forceinline__ unsigned pk_bf16(float a, float b) {
    unsigned r;
    asm("v_cvt_pk_bf16_f32 %0, %1, %2" : "=v"(r) : "v"(a), "v"(b));
    return r;
}

// ---------------- fused fp32 -> bf16 conversion (x, w_attn, w_proj) ----------------
__global__ void f2bf3_kernel(const float* __restrict__ x, const float* __restrict__ wa,
                             const float* __restrict__ wp, __bf16* __restrict__ xb,
                             __bf16* __restrict__ wab, __bf16* __restrict__ wpb) {
    int i = blockIdx.x * blockDim.x + threadIdx.x;   // float4 index, total 3145728
    const float* in; __bf16* out; int off;
    if (i < 2097152)      { in = x;  out = xb;  off = i; }
    else if (i < 2883584) { in = wa; out = wab; off = i - 2097152; }
    else                  { in = wp; out = wpb; off = i - 2883584; }
    float4 v = *(const float4*)(in + off * 4);
    bf16x4_t o;
    o[0] = (__bf16)v.x; o[1] = (__bf16)v.y; o[2] = (__bf16)v.z; o[3] = (__bf16)v.w;
    *(bf16x4_t*)(out + off * 4) = o;
}

// ---------------- GEMM1: m201-style 256x256 8-phase, BK=64 (proven R9) ----------------
__global__ __launch_bounds__(512, 2) void gemm1_m201(const __bf16* __restrict__ A,
                                                     const __bf16* __restrict__ Bt,
                                                     __bf16* __restrict__ Cqk,
                                                     __bf16* __restrict__ Vg,
                                                     int M, int N, int K) {
    __shared__ __bf16 As[2][256 * 64];
    __shared__ __bf16 Bs[2][256 * 64];

    const int tid  = threadIdx.x;
    const int lane = tid & 63;
    const int wid  = tid >> 6;
    const int wm   = wid >> 2;
    const int wn   = wid & 3;

    int fl = blockIdx.x;
    fl = (fl & 7) * (gridDim.x >> 3) + (fl >> 3);
    const int m0 = (fl / 12) * 256;
    const int n0 = (fl % 12) * 256;

    const int lr = lane & 15;
    const int lg = lane >> 4;
    const int cr = lg * 4;
    const int srow = lane >> 3;
    const int gcol = (((lane & 7) ^ srow) << 3);

    f32x4_t acc[8][4];
#pragma unroll
    for (int i = 0; i < 8; ++i)
#pragma unroll
        for (int j = 0; j < 4; ++j)
            acc[i][j] = (f32x4_t){0.f, 0.f, 0.f, 0.f};

    const int NT = K >> 6;
    const int NI = NT >> 1;

    bf16x8_t af[4][2], bf0[2][2], bf1[2][2];

    auto stA = [&](int kt, int buf, int half) {
        const __bf16* Ab = A + (size_t)m0 * K + (size_t)kt * 64;
        const int s0 = half * 16 + wid, s1 = s0 + 8;
        gload_lds16(Ab + (size_t)(s0 * 8 + srow) * K + gcol, &As[buf][s0 * 512]);
        gload_lds16(Ab + (size_t)(s1 * 8 + srow) * K + gcol, &As[buf][s1 * 512]);
    };
    auto stB = [&](int kt, int buf, int half) {
        const __bf16* Bb = Bt + (size_t)n0 * K + (size_t)kt * 64;
        const int s0 = half * 16 + wid, s1 = s0 + 8;
        gload_lds16(Bb + (size_t)(s0 * 8 + srow) * K + gcol, &Bs[buf][s0 * 512]);
        gload_lds16(Bb + (size_t)(s1 * 8 + srow) * K + gcol, &Bs[buf][s1 * 512]);
    };
    auto dsA = [&](const __bf16* Ab, int mfh) {
#pragma unroll
        for (int mf = 0; mf < 4; ++mf)
#pragma unroll
            for (int kk = 0; kk < 2; ++kk) {
                const int row = wm * 128 + (mfh * 4 + mf) * 16 + lr;
                const int g   = kk * 4 + lg;
                af[mf][kk] = *(const bf16x8_t*)&Ab[row * 64 + ((g ^ (row & 7)) << 3)];
            }
    };
    auto dsB = [&](const __bf16* Bb, int nfh, bf16x8_t (&dst)[2][2]) {
#pragma unroll
        for (int nfp = 0; nfp < 2; ++nfp)
#pragma unroll
            for (int kk = 0; kk < 2; ++kk) {
                const int row = wn * 64 + (nfh * 2 + nfp) * 16 + lr;
                const int g   = kk * 4 + lg;
                dst[nfp][kk] = *(const bf16x8_t*)&Bb[row * 64 + ((g ^ (row & 7)) << 3)];
            }
    };
    auto MF = [&](int mfh, bf16x8_t (&bfr)[2][2], int nfh) {
        __builtin_amdgcn_s_setprio(1);
#pragma unroll
        for (int mf = 0; mf < 4; ++mf)
#pragma unroll
            for (int nfp = 0; nfp < 2; ++nfp) {
                const int ai = mfh * 4 + mf, bi = nfh * 2 + nfp;
                acc[ai][bi] = __builtin_amdgcn_mfma_f32_16x16x32_bf16(af[mf][0], bfr[nfp][0], acc[ai][bi], 0, 0, 0);
                acc[ai][bi] = __builtin_amdgcn_mfma_f32_16x16x32_bf16(af[mf][1], bfr[nfp][1], acc[ai][bi], 0, 0, 0);
            }
        __builtin_amdgcn_s_setprio(0);
    };

#define BAR() __builtin_amdgcn_s_barrier()
#define LGK0() asm volatile("s_waitcnt lgkmcnt(0)" ::: "memory")

    stA(0, 0, 0); stA(0, 0, 1); stB(0, 0, 0); stB(0, 0, 1);
    stB(1, 1, 0); stB(1, 1, 1);
    asm volatile("s_waitcnt vmcnt(4)" ::: "memory");
    BAR();

    for (int it = 0; it < NI; ++it) {
        const int t1 = 2 * it + 1, t2 = 2 * it + 2, t3 = 2 * it + 3;
        const bool lastit = (it == NI - 1);

        dsA(As[0], 0); dsB(Bs[0], 0, bf0);
        stA(t1, 1, 0);
        BAR(); LGK0();
        MF(0, bf0, 0);
        BAR();

        dsB(Bs[0], 1, bf1);
        stA(t1, 1, 1);
        BAR(); LGK0();
        MF(0, bf1, 1);
        BAR();

        dsA(As[0], 1);
        if (!lastit) stB(t2, 0, 0);
        BAR(); LGK0();
        MF(1, bf0, 0);
        BAR();

        if (!lastit) stB(t2, 0, 1);
        if (lastit) asm volatile("s_waitcnt vmcnt(0)" ::: "memory");
        else        asm volatile("s_waitcnt vmcnt(4)" ::: "memory");
        BAR();
        MF(1, bf1, 1);
        BAR();

        dsA(As[1], 0); dsB(Bs[1], 0, bf0);
        if (!lastit) stA(t2, 0, 0);
        BAR(); LGK0();
        MF(0, bf0, 0);
        BAR();

        dsB(Bs[1], 1, bf1);
        if (!lastit) stA(t2, 0, 1);
        BAR(); LGK0();
        MF(0, bf1, 1);
        BAR();

        dsA(As[1], 1);
        if (!lastit) stB(t3, 1, 0);
        BAR(); LGK0();
        MF(1, bf0, 0);
        BAR();

        if (!lastit) stB(t3, 1, 1);
        if (lastit) asm volatile("s_waitcnt vmcnt(0)" ::: "memory");
        else        asm volatile("s_waitcnt vmcnt(4)" ::: "memory");
        BAR();
        MF(1, bf1, 1);
        BAR();
    }
#undef BAR
#undef LGK0

    if (n0 < 2048) {
#pragma unroll
        for (int mf = 0; mf < 8; ++mf)
#pragma unroll
            for (int nf = 0; nf < 4; ++nf)
#pragma unroll
                for (int r = 0; r < 4; ++r) {
                    int row = m0 + wm * 128 + mf * 16 + cr + r;
                    int col = n0 + wn * 64 + nf * 16 + lr;
                    Cqk[(size_t)row * 2048 + col] = (__bf16)acc[mf][nf][r];
                }
    } else {
#pragma unroll
        for (int mf = 0; mf < 8; ++mf) {
            const int row0 = m0 + wm * 128 + mf * 16 + cr;
            const int bb   = row0 >> 11;
            const int tt   = row0 & 2047;
#pragma unroll
            for (int nf = 0; nf < 4; ++nf) {
                const int c3 = n0 + wn * 64 + nf * 16 + lr - 2048;
                const int hh = c3 >> 6, dd = c3 & 63;
                bf16x4_t pv;
#pragma unroll
                for (int r = 0; r < 4; ++r) pv[r] = (__bf16)acc[mf][nf][r];
                *(bf16x4_t*)&Vg[((size_t)(bb * 16 + hh) * 64 + dd) * 2048 + tt] = pv;
            }
        }
    }
}

// ---------------- bf16 GEMM (m97-style 128x128, proven): C = A * Bt^T ----------------
template <typename OutT>
__global__ __launch_bounds__(256) void gemm_bt(const __bf16* __restrict__ A,
                                               const __bf16* __restrict__ Bt,
                                               OutT* __restrict__ C,
                                               int M, int N, int K) {
    __shared__ __bf16 As[128 * 32];
    __shared__ __bf16 Bs[128 * 32];

    const int tid  = threadIdx.x;
    const int lane = tid & 63;
    const int wid  = tid >> 6;
    const int wm   = wid >> 1;
    const int wn   = wid & 1;

    const int nwg = gridDim.x * gridDim.y;
    int fl = blockIdx.y * gridDim.x + blockIdx.x;
    fl = (fl & 7) * (nwg >> 3) + (fl >> 3);
    const int m0 = (fl / gridDim.x) * 128;
    const int n0 = (fl % gridDim.x) * 128;

    const int lr = lane & 15;
    const int lk = (lane >> 4) * 8;
    const int cr = (lane >> 4) * 4;

    f32x4_t acc[4][4];
    for (int i = 0; i < 4; ++i)
        for (int j = 0; j < 4; ++j)
            acc[i][j] = (f32x4_t){0.f, 0.f, 0.f, 0.f};

    for (int k0 = 0; k0 < K; k0 += 32) {
        __syncthreads();
        for (int i = 0; i < 2; ++i) {
            int flat = i * 256 + tid;
            int row  = flat >> 2;
            int col  = (flat & 3) * 8;
            gload_lds16(&A[(size_t)(m0 + row) * K + k0 + col], &As[(size_t)(i * 256 + wid * 64) * 8]);
            gload_lds16(&Bt[(size_t)(n0 + row) * K + k0 + col], &Bs[(size_t)(i * 256 + wid * 64) * 8]);
        }
        __syncthreads();

        bf16x8_t af[4], bfr[4];
        for (int mf = 0; mf < 4; ++mf)
            af[mf] = *(const bf16x8_t*)&As[(wm * 64 + mf * 16 + lr) * 32 + lk];
        for (int nf = 0; nf < 4; ++nf)
            bfr[nf] = *(const bf16x8_t*)&Bs[(wn * 64 + nf * 16 + lr) * 32 + lk];
        for (int mf = 0; mf < 4; ++mf)
            for (int nf = 0; nf < 4; ++nf)
                acc[mf][nf] = __builtin_amdgcn_mfma_f32_16x16x32_bf16(af[mf], bfr[nf], acc[mf][nf], 0, 0, 0);
    }

    for (int mf = 0; mf < 4; ++mf)
        for (int nf = 0; nf < 4; ++nf)
            for (int r = 0; r < 4; ++r) {
                int row = m0 + wm * 64 + mf * 16 + cr + r;
                int col = n0 + wn * 64 + nf * 16 + lr;
                C[(size_t)row * N + col] = (OutT)acc[mf][nf][r];
            }
}

// ---------------- flash attention (causal), v7: 32x32 MFMA + in-register P ----------------
// QBLK=128, 4 waves x 32 q-rows, KVBLK=128, 256 threads. Swapped QK^T at 32x32
// puts each lane's full S row (64 of 128 keys; partner lane^32 holds the rest)
// in registers; P goes to PV via cvt_pk_bf16 + permlane32_swap (no LDS).
// Ks[128][64] slot=g^(key&7); Vt[64][128] slot=g^(d&7) from pre-transposed Vg.
__global__ __launch_bounds__(256, 2) void attn_kernel(const __bf16* __restrict__ qkv,  // [8192][2048] Q|K
                                                      const __bf16* __restrict__ Vg,   // [(b*16+h)*64+d][2048]
                                                      __bf16* __restrict__ y) {
    const int T = 2048, LD = 2048;
    const int orig = blockIdx.x;
    const int bidx = ((orig & 7) << 6) + (orig >> 3);   // XCD swizzle (512 % 8 == 0)
    const int pair = bidx & 7;
    const int h    = (bidx >> 3) & 15;
    const int b    = bidx >> 7;

    __shared__ __bf16 Ks[128 * 64];   // [key][granule swizzled]
    __shared__ __bf16 Vt[64 * 128];   // [d][granule swizzled]

    const int tid  = threadIdx.x;
    const int lane = tid & 63;
    const int w    = tid >> 6;        // 0..3
    const int l31  = lane & 31;
    const int hi   = lane >> 5;

    const __bf16* qg  = qkv + (size_t)b * T * LD + h * 64;
    const __bf16* kg  = qg + 1024;
    const __bf16* Vgb = Vg + (size_t)(b * 16 + h) * 64 * 2048;

    const float CE    = 0.125f * 1.44269504f;
    const float DEFER = 44.0f;

    // K staging: c = tid&7 (granule), r8 = tid>>3; rows r8 + 32*jj
    const int kc = tid & 7;
    const int kr8 = tid >> 3;
    const int kslot = (kc ^ (kr8 & 7)) << 3;
    // V staging: c = tid&15, d8 = tid>>4; rows d8 + 16*jj
    const int vc = tid & 15;
    const int vd8 = tid >> 4;
    const int vslot = (vc ^ (vd8 & 7)) << 3;

    for (int pass = 0; pass < 2; ++pass) {
        const int qs  = pass ? 15 - pair : pair;
        const int qt0 = qs * 128;
        const int nt  = qs + 1;
        const int qgl = qt0 + w * 32 + l31;

        // Q fragments: 4 k-steps x 8 bf16 (col=q, k=d run 8*hi..)
        bf16x8_t qreg[4];
#pragma unroll
        for (int ks = 0; ks < 4; ++ks)
            qreg[ks] = *(const bf16x8_t*)&qg[(size_t)qgl * LD + ks * 16 + 8 * hi];

        // tile-0 staged loads
        bf16x8_t kreg[4], vreg[4];
#pragma unroll
        for (int jj = 0; jj < 4; ++jj)
            kreg[jj] = *(const bf16x8_t*)&kg[(size_t)(kr8 + 32 * jj) * LD + kc * 8];
#pragma unroll
        for (int jj = 0; jj < 4; ++jj)
            vreg[jj] = *(const bf16x8_t*)&Vgb[(size_t)(vd8 + 16 * jj) * 2048 + vc * 8];

        f32x16_t o0 = (f32x16_t)(0.f), o1 = (f32x16_t)(0.f);
        float m_r = -3.0e38f, l_r = 0.f;

        for (int t = 0; t < nt; ++t) {
            __syncthreads();   // prev tile reads done; staged regs valid

            // write staged tile to LDS (swizzled)
#pragma unroll
            for (int jj = 0; jj < 4; ++jj)
                *(bf16x8_t*)&Ks[(kr8 + 32 * jj) * 64 + kslot] = kreg[jj];
#pragma unroll
            for (int jj = 0; jj < 4; ++jj)
                *(bf16x8_t*)&Vt[(vd8 + 16 * jj) * 128 + vslot] = vreg[jj];

            __syncthreads();   // tile visible

            // prefetch next tile into regs (hides under compute)
            if (t + 1 < nt) {
                const size_t kb0 = (size_t)(t + 1) * 128;
#pragma unroll
                for (int jj = 0; jj < 4; ++jj)
                    kreg[jj] = *(const bf16x8_t*)&kg[(kb0 + kr8 + 32 * jj) * LD + kc * 8];
#pragma unroll
                for (int jj = 0; jj < 4; ++jj)
                    vreg[jj] = *(const bf16x8_t*)&Vgb[(size_t)(vd8 + 16 * jj) * 2048 + kb0 + vc * 8];
            }

            // --- S^T = K Q^T : s[kb] covers keys kb*32 + crow(reg,hi), q = l31 ---
            f32x16_t s[4];
            __builtin_amdgcn_s_setprio(1);
#pragma unroll
            for (int kb = 0; kb < 4; ++kb) {
                const int key = kb * 32 + l31;
                const int sw7 = key & 7;
                s[kb] = (f32x16_t)(0.f);
#pragma unroll
                for (int ks = 0; ks < 4; ++ks) {
                    bf16x8_t kf = *(const bf16x8_t*)&Ks[key * 64 + (((2 * ks + hi) ^ sw7) << 3)];
                    s[kb] = __builtin_amdgcn_mfma_f32_32x32x16_bf16(kf, qreg[ks], s[kb], 0, 0, 0);
                }
            }
            __builtin_amdgcn_s_setprio(0);

            // --- causal mask (diagonal tile only) ---
            if (t == nt - 1) {
                const int ql = w * 32 + l31;
#pragma unroll
                for (int kb = 0; kb < 4; ++kb)
#pragma unroll
                    for (int r = 0; r < 16; ++r) {
                        const int key = kb * 32 + (r & 3) + 8 * (r >> 2) + 4 * hi;
                        if (key > ql) s[kb][r] = -1.0e30f;
                    }
            }

            // --- online softmax (lane owns 64 of 128 keys for its q; partner = lane^32) ---
            float pm = s[0][0];
#pragma unroll
            for (int kb = 0; kb < 4; ++kb)
#pragma unroll
                for (int r = 0; r < 16; ++r) pm = fmaxf(pm, s[kb][r]);

            if (!__all(pm <= m_r + DEFER)) {
                pm = fmaxf(pm, __shfl_xor(pm, 32));
                const float mn    = fmaxf(m_r, pm);
                const float alpha = exp2f((m_r - mn) * CE);
                l_r *= alpha;
#pragma unroll
                for (int r = 0; r < 16; ++r) { o0[r] *= alpha; o1[r] *= alpha; }
                m_r = mn;
            }
            const float mce = m_r * CE;

            float rs = 0.f;
#pragma unroll
            for (int kb = 0; kb < 4; ++kb)
#pragma unroll
                for (int r = 0; r < 16; ++r) {
                    float pv = exp2f(fmaf(s[kb][r], CE, -mce));
                    s[kb][r] = pv;
                    rs += pv;
                }
            rs += __shfl_xor(rs, 32);
            l_r += rs;

            // --- PV: O^T += V^T P^T; P fragments built in-register ---
            __builtin_amdgcn_s_setprio(1);
#pragma unroll
            for (int ks = 0; ks < 8; ++ks) {
                const int kb = ks >> 1;
                const int rb = 8 * (ks & 1);
                unsigned L0 = pk_bf16(s[kb][rb + 0], s[kb][rb + 1]);
                unsigned L1 = pk_bf16(s[kb][rb + 2], s[kb][rb + 3]);
                unsigned H0 = pk_bf16(s[kb][rb + 4], s[kb][rb + 5]);
                unsigned H1 = pk_bf16(s[kb][rb + 6], s[kb][rb + 7]);
                asm("v_permlane32_swap_b32 %0, %1" : "+v"(L0), "+v"(H0));
                asm("v_permlane32_swap_b32 %0, %1" : "+v"(L1), "+v"(H1));
                union { unsigned u[4]; bf16x8_t v; } uf;
                uf.u[0] = L0; uf.u[1] = L1; uf.u[2] = H0; uf.u[3] = H1;
                const int gv = 2 * ks + hi;
                {
                    const int d = l31;          // db = 0
                    bf16x8_t vf = *(const bf16x8_t*)&Vt[d * 128 + ((gv ^ (d & 7)) << 3)];
                    o0 = __builtin_amdgcn_mfma_f32_32x32x16_bf16(vf, uf.v, o0, 0, 0, 0);
                }
                {
                    const int d = 32 + l31;     // db = 1
                    bf16x8_t vf = *(const bf16x8_t*)&Vt[d * 128 + ((gv ^ (d & 7)) << 3)];
                    o1 = __builtin_amdgcn_mfma_f32_32x32x16_bf16(vf, uf.v, o1, 0, 0, 0);
                }
            }
            __builtin_amdgcn_s_setprio(0);
        }

        // --- epilogue: lane owns q = qgl, d rows (reg&3)+8*(reg>>2)+4*hi per db ---
        const float inv = 1.0f / l_r;
        __bf16* yrow = y + (size_t)(b * T + qgl) * 1024 + h * 64;
#pragma unroll
        for (int tq = 0; tq < 4; ++tq) {
            bf16x4_t ov0, ov1;
#pragma unroll
            for (int u = 0; u < 4; ++u) {
                ov0[u] = (__bf16)(o0[tq * 4 + u] * inv);
                ov1[u] = (__bf16)(o1[tq * 4 + u] * inv);
            }
            const int dl = 8 * tq + 4 * hi;
            *(bf16x4_t*)&yrow[dl]      = ov0;
            *(bf16x4_t*)&yrow[32 + dl] = ov1;
        }
    }
}

// ---------------- launch ----------------
extern "C" void kernel_launch(void* const* d_in, const int* in_sizes, int n_in,
                              void* d_out, int out_size, void* d_ws, size_t ws_size,
                              hipStream_t stream) {
    const float* x      = (const float*)d_in[0];
    const float* w_attn = (const float*)d_in[1];
    const float* w_proj = (const float*)d_in[2];
    float* out = (float*)d_out;

    char* ws = (char*)d_ws;
    __bf16* xb   = (__bf16*)(ws);                      // 8192*1024      = 16 MB
    __bf16* wab  = (__bf16*)(ws + 16777216);           // 3072*1024      = 6 MB
    __bf16* wpb  = (__bf16*)(ws + 23068672);           // 1024*1024      = 2 MB
    __bf16* qkvb = (__bf16*)(ws + 25165824);           // 8192*2048 Q|K  = 32 MB
    __bf16* yb   = (__bf16*)(ws + 58720256);           // 8192*1024      = 16 MB
    __bf16* Vg   = (__bf16*)(ws + 75497472);           // 64*64*2048     = 16 MB

    f2bf3_kernel<<<12288, 256, 0, stream>>>(x, w_attn, w_proj, xb, wab, wpb);

    // qkv: Q/K -> qkvb [8192][2048]; V -> Vg transposed  (256x256 8-phase)
    gemm1_m201<<<384, 512, 0, stream>>>(xb, wab, qkvb, Vg, 8192, 3072, 1024);

    // flash attention -> yb [8192, 1024]
    attn_kernel<<<512, 256, 0, stream>>>(qkvb, Vg, yb);

    // out = yb @ w_proj^T  [8192, 1024] fp32
    gemm_bt<float><<<dim3(8, 64), 256, 0, stream>>>(yb, wpb, out, 8192, 1024, 1024);
}